// Round 3
// baseline (512.486 us; speedup 1.0000x reference)
//
#include <hip/hip_runtime.h>
#include <hip/hip_bf16.h>

// EdgeConv B=8,C=64,N=4096,OUT=64,K=20.
// h[b,o,n,k] = z[b,n,o] - y[b,idx_k,o];  out = leakyrelu((z - min/max_k y)*inv + bias)
#define NN 4096
#define KK 20
#define LL 12        // per-thread sorted list of GROUP keys (group = 4 consecutive m)
#define NCAND 192    // 16 lists * LL (group keys per row)
#define EXTRG 28     // groups extracted before fp64 rescore (margin 8 over 20)
#define NC 112       // EXTRG*4 candidates rescored in fp64

typedef short bf16x8 __attribute__((ext_vector_type(8)));
typedef float f32x4  __attribute__((ext_vector_type(4)));

__device__ __forceinline__ unsigned umax_(unsigned a, unsigned b){ return a > b ? a : b; }
__device__ __forceinline__ unsigned umin_(unsigned a, unsigned b){ return a < b ? a : b; }

__device__ __forceinline__ unsigned bfbits(float f) {   // fp32 -> bf16 bits, RNE
    unsigned u = __float_as_uint(f);
    return (u + 0x7FFFu + ((u >> 16) & 1u)) >> 16;
}

// ---------------- Kernel 1: transpose + xx + bf16 copy + y/z matvecs ----------------
__global__ __launch_bounds__(256, 2) void k_prep(
    const float* __restrict__ x, const float* __restrict__ W,
    float* __restrict__ xt, unsigned short* __restrict__ xbf,
    float* __restrict__ yT, float* __restrict__ zT,
    double* __restrict__ xxd, float* __restrict__ xxc)
{
    __shared__ float wS[8192];           // W row-major [o][128], 32 KB
    int tid = threadIdx.x;
    #pragma unroll
    for (int i = 0; i < 32; ++i) wS[tid + 256*i] = W[tid + 256*i];
    __syncthreads();

    int b = blockIdx.x >> 4;
    int n = ((blockIdx.x & 15) << 8) + tid;

    float xv[64];
    double xx = 0.0;
    #pragma unroll
    for (int c = 0; c < 64; ++c) {
        float v = x[((size_t)(b*64 + c) << 12) + n];
        xv[c] = v;
        xx += (double)v * (double)v;
    }
    size_t rowbase = ((size_t)b*NN + n) * 64;
    #pragma unroll
    for (int c4 = 0; c4 < 16; ++c4)
        ((float4*)(xt + rowbase))[c4] =
            make_float4(xv[4*c4], xv[4*c4+1], xv[4*c4+2], xv[4*c4+3]);
    // bf16 row (RNE), packed 2/dword
    {
        unsigned pk[32];
        #pragma unroll
        for (int i = 0; i < 32; ++i)
            pk[i] = bfbits(xv[2*i]) | (bfbits(xv[2*i+1]) << 16);
        uint4* dst = (uint4*)(xbf + rowbase);
        #pragma unroll
        for (int i = 0; i < 8; ++i)
            dst[i] = make_uint4(pk[4*i], pk[4*i+1], pk[4*i+2], pk[4*i+3]);
    }
    xxd[b*NN + n] = xx;
    xxc[b*NN + n] = 1024.f - (float)xx;     // biased so scores are always > 0

    for (int o0 = 0; o0 < 64; o0 += 16) {
        float yv[16], zv[16];
        #pragma unroll
        for (int i = 0; i < 16; ++i) {
            const float* w1 = wS + (size_t)(o0 + i) * 128;
            float a1 = 0.f, a2 = 0.f;
            #pragma unroll
            for (int c = 0; c < 64; ++c) {
                a1 = fmaf(w1[c],      xv[c], a1);
                a2 = fmaf(w1[64 + c], xv[c], a2);
            }
            yv[i] = a1; zv[i] = a1 + a2;
        }
        float4* yp = (float4*)(yT + rowbase + o0);
        float4* zp = (float4*)(zT + rowbase + o0);
        #pragma unroll
        for (int i4 = 0; i4 < 4; ++i4) {
            yp[i4] = make_float4(yv[4*i4], yv[4*i4+1], yv[4*i4+2], yv[4*i4+3]);
            zp[i4] = make_float4(zv[4*i4], zv[4*i4+1], zv[4*i4+2], zv[4*i4+3]);
        }
    }
}

// ---------------- Kernel 2: MFMA Gram + group-of-4 max + top-12 group keys ----------------
// block = 4 waves, 16 n-rows. Wave w owns m-cols [16w..16w+16) of each 64-m chunk.
// Barrier-free: each wave writes & re-reads only its own LDS columns (DS in-order/wave).
// score' = 2*dot - xx[m] + 1024 > 0 always -> positive fp32 bits compare as unsigned.
// key = (score bits & 0xFFFFFC00) | gid, gid in [0,1024) = group of 4 consecutive m.
__global__ __launch_bounds__(256) void k_topk(
    const unsigned short* __restrict__ xbf, const float* __restrict__ xxc,
    unsigned* __restrict__ cand)
{
    __shared__ float scoreS[16 * 68];    // pitch 68
    int tid  = threadIdx.x;
    int w    = tid >> 6, lane = tid & 63;
    int quad = lane >> 4, c = lane & 15;
    int b  = blockIdx.x >> 8;
    int n0 = (blockIdx.x & 255) << 4;

    const uint4* xb = (const uint4*)xbf;      // one x-row = 8 uint4

    // A fragments: row n0+c, k = quad*8+j (+32)
    size_t arow = ((size_t)b*NN + n0 + c) * 8 + quad;
    bf16x8 a0 = __builtin_bit_cast(bf16x8, xb[arow]);
    bf16x8 a1 = __builtin_bit_cast(bf16x8, xb[arow + 4]);

    unsigned keys[LL];
    #pragma unroll
    for (int i = 0; i < LL; ++i) keys[i] = 0u;

    size_t bbase = ((size_t)b*NN + 16*w + c) * 8 + quad;
    uint4 pb0 = xb[bbase], pb1 = xb[bbase + 4];
    float pxx = xxc[b*NN + 16*w + c];

    #pragma unroll 1
    for (int chunk = 0; chunk < 64; ++chunk) {
        uint4 cb0 = pb0, cb1 = pb1;
        float xxm = pxx;
        if (chunk < 63) {
            size_t nb = bbase + (size_t)(chunk + 1) * 64 * 8;
            pb0 = xb[nb]; pb1 = xb[nb + 4];
            pxx = xxc[b*NN + (chunk + 1)*64 + 16*w + c];
        }
        f32x4 acc = __builtin_amdgcn_mfma_f32_16x16x32_bf16(
            a0, __builtin_bit_cast(bf16x8, cb0), (f32x4){0.f,0.f,0.f,0.f}, 0, 0, 0);
        acc = __builtin_amdgcn_mfma_f32_16x16x32_bf16(
            a1, __builtin_bit_cast(bf16x8, cb1), acc, 0, 0, 0);

        // D layout: col=lane&15 (m), row=quad*4+reg (n). biased score = 2*dot + (1024-xx[m])
        int wb = (w << 4) + c;
        #pragma unroll
        for (int j = 0; j < 4; ++j)
            scoreS[(quad*4 + j)*68 + wb] = fmaf(2.f, acc[j], xxm);

        // scan own wave's columns: row = c, cols 16w + 4*quad .. +4  (= one group of 4 m)
        const float4* sv = (const float4*)(scoreS + c*68 + (w << 4) + (quad << 2));
        float4 s4 = *sv;
        float gm = fmaxf(fmaxf(s4.x, s4.y), fmaxf(s4.z, s4.w));
        unsigned u = __float_as_uint(gm);
        unsigned key = (u & 0xFFFFFC00u)
                     | (unsigned)((chunk << 4) | (w << 2) | quad);
        #pragma unroll
        for (int t = 0; t < LL; ++t) {      // sorted compare-exchange insert
            unsigned mx = umax_(keys[t], key);
            key = umin_(keys[t], key);
            keys[t] = mx;
        }
    }

    // row = c, list id = w*4+quad
    unsigned* cp = cand + ((size_t)(b*NN + n0 + c)) * NCAND + (w*4 + quad) * LL;
    #pragma unroll
    for (int i = 0; i < LL; ++i) cp[i] = keys[i];
}

// ---------------- Kernel 3: merge groups + fp64 refine + gather + epilogue ----------------
__global__ __launch_bounds__(256) void k_refine(
    const float* __restrict__ xt, const double* __restrict__ xxd,
    const unsigned* __restrict__ cand,
    const float* __restrict__ yT, const float* __restrict__ zT,
    const float* __restrict__ gamma, const float* __restrict__ beta,
    const float* __restrict__ rmean, const float* __restrict__ rvar,
    float* __restrict__ out)
{
    __shared__ float    xnS[16 * 64];          //  4 KB
    __shared__ unsigned keysL[16 * NCAND];     // 12 KB
    __shared__ unsigned selK[16 * EXTRG];      //  1.75 KB
    __shared__ double   selD[16 * NC];         // 14 KB
    __shared__ int      selS[16 * KK];         //  1.25 KB
    __shared__ float    outS[64 * 20];         //  5 KB

    int tid = threadIdx.x;
    int r = tid >> 4, g = tid & 15;            // 16 threads per row, quarter-wave = row
    int b = blockIdx.x >> 8;
    int n0 = (blockIdx.x & 255) << 4;
    int n = n0 + r;

    ((float4*)xnS)[tid] = ((const float4*)(xt + ((size_t)b*NN + n0) * 64))[tid];
    {
        const uint4* cs = (const uint4*)(cand + ((size_t)(b*NN + n0)) * NCAND);
        uint4* kd = (uint4*)keysL;
        kd[tid] = cs[tid]; kd[tid + 256] = cs[tid + 256]; kd[tid + 512] = cs[tid + 512];
    }
    __syncthreads();

    // extract approx-top-EXTRG groups by 16-way merge of sorted 12-lists
    {
        int head = 0;
        #pragma unroll 1
        for (int it = 0; it < EXTRG; ++it) {
            unsigned v = (head < LL) ? keysL[r*NCAND + g*LL + head] : 0u;
            unsigned vm = v;
            #pragma unroll
            for (int o = 1; o < 16; o <<= 1) vm = umax_(vm, __shfl_xor(vm, o, 16));
            if (v == vm && head < LL) { selK[r*EXTRG + it] = v; ++head; }
        }
    }
    __syncthreads();

    // fp64 exact rescore of NC = EXTRG*4 expanded candidates
    for (int i = g; i < NC; i += 16) {
        unsigned gk = selK[r*EXTRG + (i >> 2)];
        int m = (int)((gk & 1023u) << 2) + (i & 3);
        const float4* xm  = (const float4*)(xt + ((size_t)b*NN + m) * 64);
        const float4* xn4 = (const float4*)(xnS + r*64);
        double acc = 0.0;
        #pragma unroll
        for (int kk2 = 0; kk2 < 16; ++kk2) {
            float4 a = xn4[kk2], v = xm[kk2];
            acc += (double)a.x*(double)v.x + (double)a.y*(double)v.y
                 + (double)a.z*(double)v.z + (double)a.w*(double)v.w;
        }
        selD[r*NC + i] = 2.0*acc - xxd[b*NN + m];
    }
    __syncthreads();

    // exact top-20 set by rank counting (fp64 scores distinct a.s.; m's all distinct)
    for (int i = g; i < NC; i += 16) {
        double si = selD[r*NC + i];
        int cnt = 0;
        #pragma unroll 1
        for (int p = 0; p < NC; ++p) cnt += (selD[r*NC + p] > si) ? 1 : 0;
        if (cnt < KK) {
            unsigned gk = selK[r*EXTRG + (i >> 2)];
            selS[r*KK + cnt] = (int)((gk & 1023u) << 2) + (i & 3);
        }
    }
    __syncthreads();

    // gather y over the 20 neighbors; min & max per o; epilogue
    float mn[4] = { __builtin_inff(), __builtin_inff(), __builtin_inff(), __builtin_inff() };
    float mx[4] = { -__builtin_inff(), -__builtin_inff(), -__builtin_inff(), -__builtin_inff() };
    #pragma unroll 1
    for (int k = 0; k < KK; ++k) {
        int m = selS[r*KK + k];
        float4 y4 = *(const float4*)(yT + ((size_t)b*NN + m) * 64 + 4*g);
        mn[0] = fminf(mn[0], y4.x); mx[0] = fmaxf(mx[0], y4.x);
        mn[1] = fminf(mn[1], y4.y); mx[1] = fmaxf(mx[1], y4.y);
        mn[2] = fminf(mn[2], y4.z); mx[2] = fmaxf(mx[2], y4.z);
        mn[3] = fminf(mn[3], y4.w); mx[3] = fmaxf(mx[3], y4.w);
    }
    float4 z4 = *(const float4*)(zT + ((size_t)b*NN + n) * 64 + 4*g);
    float zz[4] = {z4.x, z4.y, z4.z, z4.w};
    #pragma unroll
    for (int j = 0; j < 4; ++j) {
        int o = 4*g + j;
        float inv  = gamma[o] / sqrtf(rvar[o] + 1e-5f);
        float bias = beta[o] - rmean[o] * inv;
        float ysel = (inv >= 0.f) ? mn[j] : mx[j];
        float h = (zz[j] - ysel) * inv + bias;
        outS[o*20 + r] = (h >= 0.f) ? h : 0.2f * h;
    }
    __syncthreads();
    // transpose store: thread -> (o = tid>>2, q = tid&3)
    {
        int o = tid >> 2, q = tid & 3;
        float4 v = *(const float4*)(outS + o*20 + 4*q);
        *(float4*)(out + ((size_t)(b*64 + o)) * NN + n0 + 4*q) = v;
    }
}

extern "C" void kernel_launch(void* const* d_in, const int* in_sizes, int n_in,
                              void* d_out, int out_size, void* d_ws, size_t ws_size,
                              hipStream_t stream) {
    const float* x     = (const float*)d_in[0];
    const float* W     = (const float*)d_in[1];
    const float* gamma = (const float*)d_in[2];
    const float* beta  = (const float*)d_in[3];
    const float* rmean = (const float*)d_in[4];
    const float* rvar  = (const float*)d_in[5];
    float* out = (float*)d_out;

    char* ws = (char*)d_ws;
    float*          xt   = (float*)          (ws);                          //  8 MB
    unsigned short* xbf  = (unsigned short*) (ws + ((size_t) 8 << 20));     //  4 MB
    float*          yT   = (float*)          (ws + ((size_t)12 << 20));     //  8 MB
    float*          zT   = (float*)          (ws + ((size_t)20 << 20));     //  8 MB
    double*         xxd  = (double*)         (ws + ((size_t)28 << 20));     // 256 KB
    float*          xxc  = (float*)          (ws + ((size_t)28 << 20) + (512 << 10)); // 128 KB
    unsigned*       cand = (unsigned*)       (ws + ((size_t)29 << 20));     // 24 MB

    k_prep  <<< 128, 256, 0, stream>>>(x, W, xt, xbf, yT, zT, xxd, xxc);
    k_topk  <<<2048, 256, 0, stream>>>(xbf, xxc, cand);
    k_refine<<<2048, 256, 0, stream>>>(xt, xxd, cand, yT, zT,
                                       gamma, beta, rmean, rvar, out);
}

// Round 4
// 437.630 us; speedup vs baseline: 1.1710x; 1.1710x over previous
//
#include <hip/hip_runtime.h>
#include <hip/hip_bf16.h>

// EdgeConv B=8,C=64,N=4096,OUT=64,K=20.
// h[b,o,n,k] = z[b,n,o] - y[b,idx_k,o];  out = leakyrelu((z - min/max_k y)*inv + bias)
#define NN 4096
#define KK 20
#define LL 12        // k_topk: per-thread sorted list of GROUP keys (group = 4 consecutive m)
#define NCAND 192    // 16 lists * LL group keys per row
#define EXTRG 28     // groups merged out before rescore (margin 8 over 20)
#define NC 112       // EXTRG*4 expanded candidates (fp32 rescore)
#define NF 26        // fp64-rescored finalists (margin 6 over 20)

typedef short bf16x8 __attribute__((ext_vector_type(8)));
typedef float f32x4  __attribute__((ext_vector_type(4)));

__device__ __forceinline__ unsigned umax_(unsigned a, unsigned b){ return a > b ? a : b; }
__device__ __forceinline__ unsigned umin_(unsigned a, unsigned b){ return a < b ? a : b; }

__device__ __forceinline__ unsigned bfbits(float f) {   // fp32 -> bf16 bits, RNE
    unsigned u = __float_as_uint(f);
    return (u + 0x7FFFu + ((u >> 16) & 1u)) >> 16;
}

// ---------------- Kernel 1: transpose + xx + bf16 copy + y/z matvecs ----------------
__global__ __launch_bounds__(128) void k_prep(
    const float* __restrict__ x, const float* __restrict__ W,
    float* __restrict__ xt, unsigned short* __restrict__ xbf,
    float* __restrict__ yT, float* __restrict__ zT,
    double* __restrict__ xxd, float* __restrict__ xxc)
{
    __shared__ float wS[8192];           // W row-major [o][128], 32 KB
    int tid = threadIdx.x;
    #pragma unroll
    for (int i = 0; i < 64; ++i) wS[tid + 128*i] = W[tid + 128*i];
    __syncthreads();

    int b = blockIdx.x >> 5;
    int n = ((blockIdx.x & 31) << 7) + tid;

    float xv[64];
    double xx = 0.0;
    #pragma unroll
    for (int c = 0; c < 64; ++c) {
        float v = x[((size_t)(b*64 + c) << 12) + n];
        xv[c] = v;
        xx += (double)v * (double)v;
    }
    size_t rowbase = ((size_t)b*NN + n) * 64;
    #pragma unroll
    for (int c4 = 0; c4 < 16; ++c4)
        ((float4*)(xt + rowbase))[c4] =
            make_float4(xv[4*c4], xv[4*c4+1], xv[4*c4+2], xv[4*c4+3]);
    {
        unsigned pk[32];
        #pragma unroll
        for (int i = 0; i < 32; ++i)
            pk[i] = bfbits(xv[2*i]) | (bfbits(xv[2*i+1]) << 16);
        uint4* dst = (uint4*)(xbf + rowbase);
        #pragma unroll
        for (int i = 0; i < 8; ++i)
            dst[i] = make_uint4(pk[4*i], pk[4*i+1], pk[4*i+2], pk[4*i+3]);
    }
    xxd[b*NN + n] = xx;
    xxc[b*NN + n] = 1024.f - (float)xx;     // biased so scores are always > 0

    for (int o0 = 0; o0 < 64; o0 += 16) {
        float yv[16], zv[16];
        #pragma unroll
        for (int i = 0; i < 16; ++i) {
            const float* w1 = wS + (size_t)(o0 + i) * 128;
            float a1 = 0.f, a2 = 0.f;
            #pragma unroll
            for (int c = 0; c < 64; ++c) {
                a1 = fmaf(w1[c],      xv[c], a1);
                a2 = fmaf(w1[64 + c], xv[c], a2);
            }
            yv[i] = a1; zv[i] = a1 + a2;
        }
        float4* yp = (float4*)(yT + rowbase + o0);
        float4* zp = (float4*)(zT + rowbase + o0);
        #pragma unroll
        for (int i4 = 0; i4 < 4; ++i4) {
            yp[i4] = make_float4(yv[4*i4], yv[4*i4+1], yv[4*i4+2], yv[4*i4+3]);
            zp[i4] = make_float4(zv[4*i4], zv[4*i4+1], zv[4*i4+2], zv[4*i4+3]);
        }
    }
}

// ---------------- Kernel 2: MFMA Gram + group-of-4 max + top-12 group keys ----------------
// (unchanged from R3 — barrier-free, wave-local LDS round-trip)
__global__ __launch_bounds__(256) void k_topk(
    const unsigned short* __restrict__ xbf, const float* __restrict__ xxc,
    unsigned* __restrict__ cand)
{
    __shared__ float scoreS[16 * 68];
    int tid  = threadIdx.x;
    int w    = tid >> 6, lane = tid & 63;
    int quad = lane >> 4, c = lane & 15;
    int b  = blockIdx.x >> 8;
    int n0 = (blockIdx.x & 255) << 4;

    const uint4* xb = (const uint4*)xbf;

    size_t arow = ((size_t)b*NN + n0 + c) * 8 + quad;
    bf16x8 a0 = __builtin_bit_cast(bf16x8, xb[arow]);
    bf16x8 a1 = __builtin_bit_cast(bf16x8, xb[arow + 4]);

    unsigned keys[LL];
    #pragma unroll
    for (int i = 0; i < LL; ++i) keys[i] = 0u;

    size_t bbase = ((size_t)b*NN + 16*w + c) * 8 + quad;
    uint4 pb0 = xb[bbase], pb1 = xb[bbase + 4];
    float pxx = xxc[b*NN + 16*w + c];

    #pragma unroll 1
    for (int chunk = 0; chunk < 64; ++chunk) {
        uint4 cb0 = pb0, cb1 = pb1;
        float xxm = pxx;
        if (chunk < 63) {
            size_t nb = bbase + (size_t)(chunk + 1) * 64 * 8;
            pb0 = xb[nb]; pb1 = xb[nb + 4];
            pxx = xxc[b*NN + (chunk + 1)*64 + 16*w + c];
        }
        f32x4 acc = __builtin_amdgcn_mfma_f32_16x16x32_bf16(
            a0, __builtin_bit_cast(bf16x8, cb0), (f32x4){0.f,0.f,0.f,0.f}, 0, 0, 0);
        acc = __builtin_amdgcn_mfma_f32_16x16x32_bf16(
            a1, __builtin_bit_cast(bf16x8, cb1), acc, 0, 0, 0);

        int wb = (w << 4) + c;
        #pragma unroll
        for (int j = 0; j < 4; ++j)
            scoreS[(quad*4 + j)*68 + wb] = fmaf(2.f, acc[j], xxm);

        const float4* sv = (const float4*)(scoreS + c*68 + (w << 4) + (quad << 2));
        float4 s4 = *sv;
        float gm = fmaxf(fmaxf(s4.x, s4.y), fmaxf(s4.z, s4.w));
        unsigned u = __float_as_uint(gm);
        unsigned key = (u & 0xFFFFFC00u)
                     | (unsigned)((chunk << 4) | (w << 2) | quad);
        #pragma unroll
        for (int t = 0; t < LL; ++t) {
            unsigned mx = umax_(keys[t], key);
            key = umin_(keys[t], key);
            keys[t] = mx;
        }
    }

    unsigned* cp = cand + ((size_t)(b*NN + n0 + c)) * NCAND + (w*4 + quad) * LL;
    #pragma unroll
    for (int i = 0; i < LL; ++i) cp[i] = keys[i];
}

// ---------------- Kernel 3: merge + fp32 prefilter + fp64 finalize + epilogue ----------------
// 16 rows/block, 16 threads/row (= quarter-wave). All stages wave-local -> no barriers
// until the cross-wave output transpose.
__global__ __launch_bounds__(256) void k_refine(
    const float* __restrict__ xt, const double* __restrict__ xxd,
    const float* __restrict__ xxc,
    const unsigned* __restrict__ cand,
    const float* __restrict__ yT, const float* __restrict__ zT,
    const float* __restrict__ gamma, const float* __restrict__ beta,
    const float* __restrict__ rmean, const float* __restrict__ rvar,
    float* __restrict__ out)
{
    __shared__ unsigned keysL[16 * NCAND];     // 12 KB (per-thread own 12-lists)
    __shared__ unsigned gselS[16 * EXTRG];     // 1.75 KB
    __shared__ unsigned k112S[16 * NC];        // 7 KB (per-thread own sorted 7-lists)
    __shared__ int      m26S[16 * NF];         // 1.66 KB
    __shared__ double   d26S[16 * NF];         // 3.33 KB
    __shared__ int      selS[16 * KK];         // 1.25 KB
    __shared__ float    outS[64 * 20];         // 5 KB

    int tid = threadIdx.x;
    int r = tid >> 4, g = tid & 15;
    int b = blockIdx.x >> 8;
    int n0 = (blockIdx.x & 255) << 4;
    int n = n0 + r;
    size_t brow = (size_t)b * NN;

    // own x_n chunk (only data this thread ever needs of row n)
    float4 an = *(const float4*)(xt + (brow + n) * 64 + 4*g);

    // load own 12 group keys into own LDS slot (no barrier needed: same-thread)
    {
        const uint4* cs = (const uint4*)(cand + (brow + n) * NCAND + g * LL);
        uint4* kd = (uint4*)(keysL + r*NCAND + g*LL);
        kd[0] = cs[0]; kd[1] = cs[1]; kd[2] = cs[2];
    }

    // ---- stage 2: merge 16 sorted 12-lists -> top-EXTRG groups (wave-local) ----
    {
        int head = 0;
        #pragma unroll 1
        for (int it = 0; it < EXTRG; ++it) {
            unsigned v = (head < LL) ? keysL[r*NCAND + g*LL + head] : 0u;
            unsigned vm = v;
            #pragma unroll
            for (int o = 1; o < 16; o <<= 1) vm = umax_(vm, __shfl_xor(vm, o, 16));
            if (v == vm && head < LL) { gselS[r*EXTRG + it] = v; ++head; }
        }
    }

    // ---- stage 3: fp32 cooperative rescore of NC=112 candidates ----
    // thread g loads chunk g of x_m -> wave instruction = 4 rows x 256B, coalesced
    unsigned myk[7];
    #pragma unroll 1
    for (int j = 0; j < 7; ++j) {
        #pragma unroll
        for (int t = 0; t < 16; ++t) {
            int i = j*16 + t;
            unsigned gk = gselS[r*EXTRG + (i >> 2)];
            int m = (int)((gk & 1023u) << 2) | (i & 3);
            float4 v = *(const float4*)(xt + (brow + m) * 64 + 4*g);
            float p = fmaf(an.x, v.x, fmaf(an.y, v.y, fmaf(an.z, v.z, an.w * v.w)));
            p += __shfl_xor(p, 1, 16);
            p += __shfl_xor(p, 2, 16);
            p += __shfl_xor(p, 4, 16);
            p += __shfl_xor(p, 8, 16);
            float sc = fmaf(2.f, p, xxc[brow + m]);   // biased positive
            unsigned key = (__float_as_uint(sc) & 0xFFFFFF80u) | (unsigned)i;
            if (t == g) myk[j] = key;     // each residue class has exactly 7 cands
        }
    }
    // sort own 7 keys descending (CE network), park in own LDS slot
    #pragma unroll
    for (int a = 1; a < 7; ++a)
        #pragma unroll
        for (int q = a; q > 0; --q) {
            unsigned lo = umin_(myk[q-1], myk[q]);
            myk[q-1] = umax_(myk[q-1], myk[q]);
            myk[q] = lo;
        }
    #pragma unroll
    for (int q = 0; q < 7; ++q) k112S[r*NC + g*7 + q] = myk[q];

    // ---- stage 3.5: merge -> exact top-NF of the 112 fp32 keys ----
    {
        int head = 0;
        #pragma unroll 1
        for (int it = 0; it < NF; ++it) {
            unsigned v = (head < 7) ? k112S[r*NC + g*7 + head] : 0u;
            unsigned vm = v;
            #pragma unroll
            for (int o = 1; o < 16; o <<= 1) vm = umax_(vm, __shfl_xor(vm, o, 16));
            if (v == vm && head < 7) {
                ++head;
                int i = (int)(v & 127u);
                unsigned gk = gselS[r*EXTRG + (i >> 2)];
                m26S[r*NF + it] = (int)((gk & 1023u) << 2) | (i & 3);
            }
        }
    }

    // ---- stage 4: fp64 cooperative rescore of NF finalists ----
    {
        double ax = (double)an.x, ay = (double)an.y, az = (double)an.z, aw = (double)an.w;
        #pragma unroll 2
        for (int t = 0; t < NF; ++t) {
            int m = m26S[r*NF + t];
            float4 v = *(const float4*)(xt + (brow + m) * 64 + 4*g);
            double p = ax*(double)v.x + ay*(double)v.y + az*(double)v.z + aw*(double)v.w;
            p += __shfl_xor(p, 1, 16);
            p += __shfl_xor(p, 2, 16);
            p += __shfl_xor(p, 4, 16);
            p += __shfl_xor(p, 8, 16);
            if ((t & 15) == g) d26S[r*NF + t] = 2.0*p - xxd[brow + m];
        }
    }

    // ---- stage 5: exact top-20 set by rank counting (unrolled, pipelined) ----
    #pragma unroll 1
    for (int t = g; t < NF; t += 16) {
        double st = d26S[r*NF + t];
        int cnt = 0;
        #pragma unroll
        for (int p = 0; p < NF; ++p) cnt += (d26S[r*NF + p] > st) ? 1 : 0;
        if (cnt < KK) selS[r*KK + cnt] = m26S[r*NF + t];
    }

    // ---- stage 6: gather y over 20 neighbors; min & max per o; epilogue ----
    float mn[4] = { __builtin_inff(), __builtin_inff(), __builtin_inff(), __builtin_inff() };
    float mx[4] = { -__builtin_inff(), -__builtin_inff(), -__builtin_inff(), -__builtin_inff() };
    #pragma unroll 4
    for (int k = 0; k < KK; ++k) {
        int m = selS[r*KK + k];
        float4 y4 = *(const float4*)(yT + (brow + m) * 64 + 4*g);
        mn[0] = fminf(mn[0], y4.x); mx[0] = fmaxf(mx[0], y4.x);
        mn[1] = fminf(mn[1], y4.y); mx[1] = fmaxf(mx[1], y4.y);
        mn[2] = fminf(mn[2], y4.z); mx[2] = fmaxf(mx[2], y4.z);
        mn[3] = fminf(mn[3], y4.w); mx[3] = fmaxf(mx[3], y4.w);
    }
    float4 z4 = *(const float4*)(zT + (brow + n) * 64 + 4*g);
    float zz[4] = {z4.x, z4.y, z4.z, z4.w};
    #pragma unroll
    for (int j = 0; j < 4; ++j) {
        int o = 4*g + j;
        float inv  = gamma[o] / sqrtf(rvar[o] + 1e-5f);
        float bias = beta[o] - rmean[o] * inv;
        float ysel = (inv >= 0.f) ? mn[j] : mx[j];
        float h = (zz[j] - ysel) * inv + bias;
        outS[o*20 + r] = (h >= 0.f) ? h : 0.2f * h;
    }
    __syncthreads();   // only cross-wave dependency: output transpose
    {
        int o = tid >> 2, q = tid & 3;
        float4 v = *(const float4*)(outS + o*20 + 4*q);
        *(float4*)(out + ((size_t)(b*64 + o)) * NN + n0 + 4*q) = v;
    }
}

extern "C" void kernel_launch(void* const* d_in, const int* in_sizes, int n_in,
                              void* d_out, int out_size, void* d_ws, size_t ws_size,
                              hipStream_t stream) {
    const float* x     = (const float*)d_in[0];
    const float* W     = (const float*)d_in[1];
    const float* gamma = (const float*)d_in[2];
    const float* beta  = (const float*)d_in[3];
    const float* rmean = (const float*)d_in[4];
    const float* rvar  = (const float*)d_in[5];
    float* out = (float*)d_out;

    char* ws = (char*)d_ws;
    float*          xt   = (float*)          (ws);                          //  8 MB
    unsigned short* xbf  = (unsigned short*) (ws + ((size_t) 8 << 20));     //  4 MB
    float*          yT   = (float*)          (ws + ((size_t)12 << 20));     //  8 MB
    float*          zT   = (float*)          (ws + ((size_t)20 << 20));     //  8 MB
    double*         xxd  = (double*)         (ws + ((size_t)28 << 20));     // 256 KB
    float*          xxc  = (float*)          (ws + ((size_t)28 << 20) + (512 << 10)); // 128 KB
    unsigned*       cand = (unsigned*)       (ws + ((size_t)29 << 20));     // 24 MB

    k_prep  <<< 256, 128, 0, stream>>>(x, W, xt, xbf, yT, zT, xxd, xxc);
    k_topk  <<<2048, 256, 0, stream>>>(xbf, xxc, cand);
    k_refine<<<2048, 256, 0, stream>>>(xt, xxd, xxc, cand, yT, zT,
                                       gamma, beta, rmean, rvar, out);
}

// Round 5
// 415.736 us; speedup vs baseline: 1.2327x; 1.0527x over previous
//
#include <hip/hip_runtime.h>
#include <hip/hip_bf16.h>

// EdgeConv B=8,C=64,N=4096,OUT=64,K=20.
// h[b,o,n,k] = z[b,n,o] - y[b,idx_k,o];  out = leakyrelu((z - min/max_k y)*inv + bias)
#define NN 4096
#define KK 20
#define LL 12        // k_topk: per-thread sorted list of GROUP keys (group = 4 consecutive m)
#define NCAND 192    // 16 lists * LL group keys per row
#define EXTRG 28     // groups merged out before rescore (margin 8 over 20)
#define NF 26        // fp64-rescored finalists (margin 6 over 20)

typedef short bf16x8 __attribute__((ext_vector_type(8)));
typedef float f32x4  __attribute__((ext_vector_type(4)));

__device__ __forceinline__ unsigned umax_(unsigned a, unsigned b){ return a > b ? a : b; }
__device__ __forceinline__ unsigned umin_(unsigned a, unsigned b){ return a < b ? a : b; }

__device__ __forceinline__ unsigned bfbits(float f) {   // fp32 -> bf16 bits, RNE
    unsigned u = __float_as_uint(f);
    return (u + 0x7FFFu + ((u >> 16) & 1u)) >> 16;
}
__device__ __forceinline__ float bflo(unsigned u){ return __builtin_bit_cast(float, u << 16); }
__device__ __forceinline__ float bfhi(unsigned u){ return __builtin_bit_cast(float, u & 0xFFFF0000u); }

// ---- DPP cross-lane (row = 16 lanes; row_ror:n = 0x120+n) -------------------
template<int CTRL>
__device__ __forceinline__ int dpp_mov(int v) {
    return __builtin_amdgcn_update_dpp(0, v, CTRL, 0xF, 0xF, true);
}
template<int CTRL>
__device__ __forceinline__ float dpp_addf(float v) {
    return v + __builtin_bit_cast(float, dpp_mov<CTRL>(__builtin_bit_cast(int, v)));
}
template<int CTRL>
__device__ __forceinline__ unsigned dpp_maxu(unsigned v) {
    return umax_(v, (unsigned)dpp_mov<CTRL>((int)v));
}
template<int CTRL>
__device__ __forceinline__ double dpp_addd(double v) {
    long long x = __builtin_bit_cast(long long, v);
    int lo = dpp_mov<CTRL>((int)(x & 0xFFFFFFFFll));
    int hi = dpp_mov<CTRL>((int)(x >> 32));
    long long y = (long long)(unsigned)lo | (((long long)hi) << 32);
    return v + __builtin_bit_cast(double, y);
}
__device__ __forceinline__ float rowsum16(float v) {
    v = dpp_addf<0x128>(v); v = dpp_addf<0x124>(v);
    v = dpp_addf<0x122>(v); v = dpp_addf<0x121>(v);
    return v;
}
__device__ __forceinline__ unsigned rowmax16(unsigned v) {
    v = dpp_maxu<0x128>(v); v = dpp_maxu<0x124>(v);
    v = dpp_maxu<0x122>(v); v = dpp_maxu<0x121>(v);
    return v;
}
__device__ __forceinline__ double rowsum16d(double v) {
    v = dpp_addd<0x128>(v); v = dpp_addd<0x124>(v);
    v = dpp_addd<0x122>(v); v = dpp_addd<0x121>(v);
    return v;
}

// ---------------- Kernel 1: transpose + xx + bf16 copy + y/z matvecs ----------------
__global__ __launch_bounds__(128) void k_prep(
    const float* __restrict__ x, const float* __restrict__ W,
    float* __restrict__ xt, unsigned short* __restrict__ xbf,
    float* __restrict__ yT, float* __restrict__ zT,
    double* __restrict__ xxd, float* __restrict__ xxc)
{
    __shared__ float wS[8192];           // W row-major [o][128], 32 KB
    int tid = threadIdx.x;
    #pragma unroll
    for (int i = 0; i < 64; ++i) wS[tid + 128*i] = W[tid + 128*i];
    __syncthreads();

    int b = blockIdx.x >> 5;
    int n = ((blockIdx.x & 31) << 7) + tid;

    float xv[64];
    double xx = 0.0;
    #pragma unroll
    for (int c = 0; c < 64; ++c) {
        float v = x[((size_t)(b*64 + c) << 12) + n];
        xv[c] = v;
        xx += (double)v * (double)v;
    }
    size_t rowbase = ((size_t)b*NN + n) * 64;
    #pragma unroll
    for (int c4 = 0; c4 < 16; ++c4)
        ((float4*)(xt + rowbase))[c4] =
            make_float4(xv[4*c4], xv[4*c4+1], xv[4*c4+2], xv[4*c4+3]);
    {
        unsigned pk[32];
        #pragma unroll
        for (int i = 0; i < 32; ++i)
            pk[i] = bfbits(xv[2*i]) | (bfbits(xv[2*i+1]) << 16);
        uint4* dst = (uint4*)(xbf + rowbase);
        #pragma unroll
        for (int i = 0; i < 8; ++i)
            dst[i] = make_uint4(pk[4*i], pk[4*i+1], pk[4*i+2], pk[4*i+3]);
    }
    xxd[b*NN + n] = xx;
    xxc[b*NN + n] = 1024.f - (float)xx;     // biased so scores are always > 0

    for (int o0 = 0; o0 < 64; o0 += 16) {
        float yv[16], zv[16];
        #pragma unroll
        for (int i = 0; i < 16; ++i) {
            const float* w1 = wS + (size_t)(o0 + i) * 128;
            float a1 = 0.f, a2 = 0.f;
            #pragma unroll
            for (int c = 0; c < 64; ++c) {
                a1 = fmaf(w1[c],      xv[c], a1);
                a2 = fmaf(w1[64 + c], xv[c], a2);
            }
            yv[i] = a1; zv[i] = a1 + a2;
        }
        float4* yp = (float4*)(yT + rowbase + o0);
        float4* zp = (float4*)(zT + rowbase + o0);
        #pragma unroll
        for (int i4 = 0; i4 < 4; ++i4) {
            yp[i4] = make_float4(yv[4*i4], yv[4*i4+1], yv[4*i4+2], yv[4*i4+3]);
            zp[i4] = make_float4(zv[4*i4], zv[4*i4+1], zv[4*i4+2], zv[4*i4+3]);
        }
    }
}

// ---------------- Kernel 2: MFMA Gram + group-of-4 max + top-12 group keys ----------------
// launch_bounds(256,4): 128-VGPR budget so keys[LL] stays in registers (28-VGPR
// allocation in R2-R4 indicated scratch spill of the key list).
__global__ __launch_bounds__(256, 4) void k_topk(
    const unsigned short* __restrict__ xbf, const float* __restrict__ xxc,
    unsigned* __restrict__ cand)
{
    __shared__ float scoreS[16 * 68];
    int tid  = threadIdx.x;
    int w    = tid >> 6, lane = tid & 63;
    int quad = lane >> 4, c = lane & 15;
    int b  = blockIdx.x >> 8;
    int n0 = (blockIdx.x & 255) << 4;

    const uint4* xb = (const uint4*)xbf;

    size_t arow = ((size_t)b*NN + n0 + c) * 8 + quad;
    bf16x8 a0 = __builtin_bit_cast(bf16x8, xb[arow]);
    bf16x8 a1 = __builtin_bit_cast(bf16x8, xb[arow + 4]);

    unsigned keys[LL];
    #pragma unroll
    for (int i = 0; i < LL; ++i) keys[i] = 0u;

    size_t bbase = ((size_t)b*NN + 16*w + c) * 8 + quad;
    uint4 pb0 = xb[bbase], pb1 = xb[bbase + 4];
    float pxx = xxc[b*NN + 16*w + c];

    #pragma unroll 1
    for (int chunk = 0; chunk < 64; ++chunk) {
        uint4 cb0 = pb0, cb1 = pb1;
        float xxm = pxx;
        if (chunk < 63) {
            size_t nb = bbase + (size_t)(chunk + 1) * 64 * 8;
            pb0 = xb[nb]; pb1 = xb[nb + 4];
            pxx = xxc[b*NN + (chunk + 1)*64 + 16*w + c];
        }
        f32x4 acc = __builtin_amdgcn_mfma_f32_16x16x32_bf16(
            a0, __builtin_bit_cast(bf16x8, cb0), (f32x4){0.f,0.f,0.f,0.f}, 0, 0, 0);
        acc = __builtin_amdgcn_mfma_f32_16x16x32_bf16(
            a1, __builtin_bit_cast(bf16x8, cb1), acc, 0, 0, 0);

        int wb = (w << 4) + c;
        #pragma unroll
        for (int j = 0; j < 4; ++j)
            scoreS[(quad*4 + j)*68 + wb] = fmaf(2.f, acc[j], xxm);

        const float4* sv = (const float4*)(scoreS + c*68 + (w << 4) + (quad << 2));
        float4 s4 = *sv;
        float gm = fmaxf(fmaxf(s4.x, s4.y), fmaxf(s4.z, s4.w));
        unsigned u = __float_as_uint(gm);
        unsigned key = (u & 0xFFFFFC00u)
                     | (unsigned)((chunk << 4) | (w << 2) | quad);
        #pragma unroll
        for (int t = 0; t < LL; ++t) {
            unsigned mx = umax_(keys[t], key);
            key = umin_(keys[t], key);
            keys[t] = mx;
        }
    }

    unsigned* cp = cand + ((size_t)(b*NN + n0 + c)) * NCAND + (w*4 + quad) * LL;
    #pragma unroll
    for (int i = 0; i < LL; ++i) cp[i] = keys[i];
}

// ---------------- Kernel 3: DPP merges + bf16 prefilter + fp64 finalize ----------------
// 16 rows/block, 16 threads/row (= quarter-wave = DPP row). All stages wave-local;
// register-resident sorted lists, pop-shift merges, DPP reductions (no DS shuffles).
__global__ __launch_bounds__(256, 4) void k_refine(
    const float* __restrict__ xt, const unsigned short* __restrict__ xbf,
    const double* __restrict__ xxd, const float* __restrict__ xxc,
    const unsigned* __restrict__ cand,
    const float* __restrict__ yT, const float* __restrict__ zT,
    const float* __restrict__ gamma, const float* __restrict__ beta,
    const float* __restrict__ rmean, const float* __restrict__ rvar,
    float* __restrict__ out)
{
    __shared__ __align__(16) unsigned gselS[16 * EXTRG];  // 1.75 KB
    __shared__ int      m26S[16 * NF];                    // 1.66 KB
    __shared__ double   d26S[16 * NF];                    // 3.33 KB
    __shared__ int      selS[16 * KK];                    // 1.25 KB
    __shared__ float    outS[64 * 20];                    // 5 KB

    int tid = threadIdx.x;
    int r = tid >> 4, g = tid & 15;
    int b = blockIdx.x >> 8;
    int n0 = (blockIdx.x & 255) << 4;
    int n = n0 + r;
    size_t brow = (size_t)b * NN;

    // ---- stage 1: own 12 sorted group keys -> registers ----
    unsigned keys[LL];
    {
        const uint4* cs = (const uint4*)(cand + (brow + n) * NCAND + g * LL);
        uint4 k0 = cs[0], k1 = cs[1], k2 = cs[2];
        keys[0]=k0.x; keys[1]=k0.y; keys[2]=k0.z;  keys[3]=k0.w;
        keys[4]=k1.x; keys[5]=k1.y; keys[6]=k1.z;  keys[7]=k1.w;
        keys[8]=k2.x; keys[9]=k2.y; keys[10]=k2.z; keys[11]=k2.w;
    }
    // x_n fragments: bf16 chunk (stage 3) and fp32 chunk (stage 4)
    uint2 anb = *(const uint2*)(xbf + (brow + n) * 64 + 4*g);
    float an0 = bflo(anb.x), an1 = bfhi(anb.x), an2 = bflo(anb.y), an3 = bfhi(anb.y);
    float4 an4 = *(const float4*)(xt + (brow + n) * 64 + 4*g);

    // ---- stage 2: pop-shift merge of 16 sorted lists -> top-EXTRG groups ----
    #pragma unroll 1
    for (int it = 0; it < EXTRG; ++it) {
        unsigned vm = rowmax16(keys[0]);
        bool win = (keys[0] == vm);
        #pragma unroll
        for (int q = 0; q < LL-1; ++q) keys[q] = win ? keys[q+1] : keys[q];
        keys[LL-1] = win ? 0u : keys[LL-1];
        if (g == (it & 15)) gselS[r*EXTRG + it] = vm;
    }

    // ---- stage 3: bf16 cooperative rescore of 112 candidates, per-lane 7-lists ----
    unsigned myk[7];
    #pragma unroll
    for (int j = 0; j < 7; ++j) {
        uint4 Gj = *(const uint4*)(gselS + r*EXTRG + 4*j);
        unsigned gk4[4] = {Gj.x, Gj.y, Gj.z, Gj.w};
        #pragma unroll
        for (int t = 0; t < 16; ++t) {
            unsigned gk = gk4[t >> 2];
            int m = (int)((gk & 1023u) << 2) | (t & 3);
            uint2 vb = *(const uint2*)(xbf + (brow + m) * 64 + 4*g);
            float p = an0 * bflo(vb.x);
            p = fmaf(an1, bfhi(vb.x), p);
            p = fmaf(an2, bflo(vb.y), p);
            p = fmaf(an3, bfhi(vb.y), p);
            p = rowsum16(p);
            float sc = fmaf(2.f, p, xxc[brow + m]);   // biased positive
            unsigned key = (__float_as_uint(sc) & 0xFFFFFF80u) | (unsigned)(j*16 + t);
            if (t == g) myk[j] = key;
        }
    }
    // sort own 7 keys descending (CE network)
    #pragma unroll
    for (int a = 1; a < 7; ++a)
        #pragma unroll
        for (int q = a; q > 0; --q) {
            unsigned lo = umin_(myk[q-1], myk[q]);
            myk[q-1] = umax_(myk[q-1], myk[q]);
            myk[q] = lo;
        }

    // ---- stage 3.5: pop-shift merge -> exact top-NF of the 112 fp32 keys ----
    #pragma unroll 1
    for (int it = 0; it < NF; ++it) {
        unsigned vm = rowmax16(myk[0]);
        bool win = (myk[0] == vm);
        #pragma unroll
        for (int q = 0; q < 6; ++q) myk[q] = win ? myk[q+1] : myk[q];
        myk[6] = win ? 0u : myk[6];
        if (g == (it & 15)) {
            int i = (int)(vm & 127u);
            unsigned gk = gselS[r*EXTRG + (i >> 2)];
            m26S[r*NF + it] = (int)((gk & 1023u) << 2) | (i & 3);
        }
    }

    // ---- stage 4: fp64 cooperative rescore of NF finalists (DPP reduce) ----
    {
        double ax = (double)an4.x, ay = (double)an4.y,
               az = (double)an4.z, aw = (double)an4.w;
        #pragma unroll 2
        for (int t = 0; t < NF; ++t) {
            int m = m26S[r*NF + t];
            float4 v = *(const float4*)(xt + (brow + m) * 64 + 4*g);
            double p = ax*(double)v.x + ay*(double)v.y + az*(double)v.z + aw*(double)v.w;
            p = rowsum16d(p);
            if ((t & 15) == g) d26S[r*NF + t] = 2.0*p - xxd[brow + m];
        }
    }

    // ---- stage 5: exact top-20 set by rank counting ----
    #pragma unroll 1
    for (int t = g; t < NF; t += 16) {
        double st = d26S[r*NF + t];
        int cnt = 0;
        #pragma unroll
        for (int p = 0; p < NF; ++p) cnt += (d26S[r*NF + p] > st) ? 1 : 0;
        if (cnt < KK) selS[r*KK + cnt] = m26S[r*NF + t];
    }

    // ---- stage 6: gather y over 20 neighbors; min & max per o; epilogue ----
    float mn[4] = { __builtin_inff(), __builtin_inff(), __builtin_inff(), __builtin_inff() };
    float mx[4] = { -__builtin_inff(), -__builtin_inff(), -__builtin_inff(), -__builtin_inff() };
    #pragma unroll 4
    for (int k = 0; k < KK; ++k) {
        int m = selS[r*KK + k];
        float4 y4 = *(const float4*)(yT + (brow + m) * 64 + 4*g);
        mn[0] = fminf(mn[0], y4.x); mx[0] = fmaxf(mx[0], y4.x);
        mn[1] = fminf(mn[1], y4.y); mx[1] = fmaxf(mx[1], y4.y);
        mn[2] = fminf(mn[2], y4.z); mx[2] = fmaxf(mx[2], y4.z);
        mn[3] = fminf(mn[3], y4.w); mx[3] = fmaxf(mx[3], y4.w);
    }
    float4 z4 = *(const float4*)(zT + (brow + n) * 64 + 4*g);
    float zz[4] = {z4.x, z4.y, z4.z, z4.w};
    #pragma unroll
    for (int j = 0; j < 4; ++j) {
        int o = 4*g + j;
        float inv  = gamma[o] / sqrtf(rvar[o] + 1e-5f);
        float bias = beta[o] - rmean[o] * inv;
        float ysel = (inv >= 0.f) ? mn[j] : mx[j];
        float h = (zz[j] - ysel) * inv + bias;
        outS[o*20 + r] = (h >= 0.f) ? h : 0.2f * h;
    }
    __syncthreads();   // only cross-wave dependency: output transpose
    {
        int o = tid >> 2, q = tid & 3;
        float4 v = *(const float4*)(outS + o*20 + 4*q);
        *(float4*)(out + ((size_t)(b*64 + o)) * NN + n0 + 4*q) = v;
    }
}

extern "C" void kernel_launch(void* const* d_in, const int* in_sizes, int n_in,
                              void* d_out, int out_size, void* d_ws, size_t ws_size,
                              hipStream_t stream) {
    const float* x     = (const float*)d_in[0];
    const float* W     = (const float*)d_in[1];
    const float* gamma = (const float*)d_in[2];
    const float* beta  = (const float*)d_in[3];
    const float* rmean = (const float*)d_in[4];
    const float* rvar  = (const float*)d_in[5];
    float* out = (float*)d_out;

    char* ws = (char*)d_ws;
    float*          xt   = (float*)          (ws);                          //  8 MB
    unsigned short* xbf  = (unsigned short*) (ws + ((size_t) 8 << 20));     //  4 MB
    float*          yT   = (float*)          (ws + ((size_t)12 << 20));     //  8 MB
    float*          zT   = (float*)          (ws + ((size_t)20 << 20));     //  8 MB
    double*         xxd  = (double*)         (ws + ((size_t)28 << 20));     // 256 KB
    float*          xxc  = (float*)          (ws + ((size_t)28 << 20) + (512 << 10)); // 128 KB
    unsigned*       cand = (unsigned*)       (ws + ((size_t)29 << 20));     // 24 MB

    k_prep  <<< 256, 128, 0, stream>>>(x, W, xt, xbf, yT, zT, xxd, xxc);
    k_topk  <<<2048, 256, 0, stream>>>(xbf, xxc, cand);
    k_refine<<<2048, 256, 0, stream>>>(xt, xbf, xxd, xxc, cand, yT, zT,
                                       gamma, beta, rmean, rvar, out);
}

// Round 6
// 315.230 us; speedup vs baseline: 1.6258x; 1.3188x over previous
//
#include <hip/hip_runtime.h>
#include <hip/hip_bf16.h>

// EdgeConv B=8,C=64,N=4096,OUT=64,K=20.
// h[b,o,n,k] = z[b,n,o] - y[b,idx_k,o];  out = leakyrelu((z - min/max_k y)*inv + bias)
#define NN 4096
#define KK 20
#define LL 12        // per-thread sorted list of GROUP keys (group = 4 consecutive m)
#define NCAND 192    // 16 lists * LL group keys per row
#define EXTRG 28     // groups merged out before rescore (margin 8 over 20)
#define NF 26        // fp64-rescored finalists (margin 6 over 20)

typedef short bf16x8 __attribute__((ext_vector_type(8)));
typedef float f32x4  __attribute__((ext_vector_type(4)));

__device__ __forceinline__ unsigned umax_(unsigned a, unsigned b){ return a > b ? a : b; }
__device__ __forceinline__ unsigned umin_(unsigned a, unsigned b){ return a < b ? a : b; }

__device__ __forceinline__ unsigned bfbits(float f) {   // fp32 -> bf16 bits, RNE
    unsigned u = __float_as_uint(f);
    return (u + 0x7FFFu + ((u >> 16) & 1u)) >> 16;
}
__device__ __forceinline__ float bflo(unsigned u){ return __builtin_bit_cast(float, u << 16); }
__device__ __forceinline__ float bfhi(unsigned u){ return __builtin_bit_cast(float, u & 0xFFFF0000u); }

__device__ __forceinline__ bf16x8 packfrag(float4 lo, float4 hi) {
    uint4 u = make_uint4(bfbits(lo.x) | (bfbits(lo.y) << 16),
                         bfbits(lo.z) | (bfbits(lo.w) << 16),
                         bfbits(hi.x) | (bfbits(hi.y) << 16),
                         bfbits(hi.z) | (bfbits(hi.w) << 16));
    return __builtin_bit_cast(bf16x8, u);
}

// ---- DPP cross-lane (row = 16 lanes; row_ror:n = 0x120+n) -------------------
template<int CTRL>
__device__ __forceinline__ int dpp_mov(int v) {
    return __builtin_amdgcn_update_dpp(0, v, CTRL, 0xF, 0xF, true);
}
template<int CTRL>
__device__ __forceinline__ float dpp_addf(float v) {
    return v + __builtin_bit_cast(float, dpp_mov<CTRL>(__builtin_bit_cast(int, v)));
}
template<int CTRL>
__device__ __forceinline__ unsigned dpp_maxu(unsigned v) {
    return umax_(v, (unsigned)dpp_mov<CTRL>((int)v));
}
template<int CTRL>
__device__ __forceinline__ double dpp_addd(double v) {
    long long x = __builtin_bit_cast(long long, v);
    int lo = dpp_mov<CTRL>((int)(x & 0xFFFFFFFFll));
    int hi = dpp_mov<CTRL>((int)(x >> 32));
    long long y = (long long)(unsigned)lo | (((long long)hi) << 32);
    return v + __builtin_bit_cast(double, y);
}
__device__ __forceinline__ float rowsum16(float v) {
    v = dpp_addf<0x128>(v); v = dpp_addf<0x124>(v);
    v = dpp_addf<0x122>(v); v = dpp_addf<0x121>(v);
    return v;
}
__device__ __forceinline__ unsigned rowmax16(unsigned v) {
    v = dpp_maxu<0x128>(v); v = dpp_maxu<0x124>(v);
    v = dpp_maxu<0x122>(v); v = dpp_maxu<0x121>(v);
    return v;
}
__device__ __forceinline__ double rowsum16d(double v) {
    v = dpp_addd<0x128>(v); v = dpp_addd<0x124>(v);
    v = dpp_addd<0x122>(v); v = dpp_addd<0x121>(v);
    return v;
}

// ---------------- Kernel 1: transpose + xx + bf16 copy + MFMA y/z ----------------
// 256 blocks x 128 threads; each thread owns one n-row for the transpose part,
// then each wave MFMAs y/z for its 64 rows (A = W rows -> D holds 4 consecutive o
// per thread for a fixed n -> direct bf16-pair packing, no output transpose).
__global__ __launch_bounds__(128) void k_prep(
    const float* __restrict__ x, const float* __restrict__ W,
    float* __restrict__ xt, unsigned short* __restrict__ xbf,
    unsigned short* __restrict__ ybf, unsigned short* __restrict__ zbf,
    double* __restrict__ xxd, float* __restrict__ xxc)
{
    __shared__ __align__(16) unsigned xS[128 * 36];   // bf16 rows, pitch 36 dwords
    int tid = threadIdx.x;
    int w = tid >> 6, lane = tid & 63, quad = lane >> 4, c = lane & 15;
    int fid = blockIdx.x * 128 + tid;          // 0..32767
    int b = fid >> 12, n = fid & 4095;
    size_t brow = (size_t)b * NN;

    float xv[64];
    double xx = 0.0;
    #pragma unroll
    for (int cc = 0; cc < 64; ++cc) {
        float v = x[((size_t)(b*64 + cc) << 12) + n];
        xv[cc] = v;
        xx += (double)v * (double)v;
    }
    size_t rowbase = (brow + n) * 64;
    #pragma unroll
    for (int c4 = 0; c4 < 16; ++c4)
        ((float4*)(xt + rowbase))[c4] =
            make_float4(xv[4*c4], xv[4*c4+1], xv[4*c4+2], xv[4*c4+3]);
    {
        unsigned pk[32];
        #pragma unroll
        for (int i = 0; i < 32; ++i)
            pk[i] = bfbits(xv[2*i]) | (bfbits(xv[2*i+1]) << 16);
        uint4* dst = (uint4*)(xbf + rowbase);
        #pragma unroll
        for (int i = 0; i < 8; ++i)
            dst[i] = make_uint4(pk[4*i], pk[4*i+1], pk[4*i+2], pk[4*i+3]);
        #pragma unroll
        for (int i = 0; i < 32; ++i) xS[tid*36 + i] = pk[i];
    }
    xxd[brow + n] = xx;
    xxc[brow + n] = 1024.f - (float)xx;     // biased so scores are always > 0

    // ---- MFMA y/z: wave-local (waves read only their own 64 LDS rows) ----
    const float4* W4 = (const float4*)W;    // W row = 32 float4
    #pragma unroll 1
    for (int t = 0; t < 4; ++t) {
        int lrow = w*64 + t*16 + c;
        uint4 xb0 = *(const uint4*)(xS + lrow*36 + quad*4);
        uint4 xb1 = *(const uint4*)(xS + lrow*36 + 16 + quad*4);
        bf16x8 bb0 = __builtin_bit_cast(bf16x8, xb0);
        bf16x8 bb1 = __builtin_bit_cast(bf16x8, xb1);
        int nw = ((blockIdx.x * 128 + w*64 + t*16 + c) & 4095);
        #pragma unroll
        for (int ot = 0; ot < 4; ++ot) {
            const float4* wr = W4 + (size_t)(ot*16 + c) * 32;
            bf16x8 w1a = packfrag(wr[quad*2],      wr[quad*2 + 1]);
            bf16x8 w1b = packfrag(wr[8 + quad*2],  wr[8 + quad*2 + 1]);
            bf16x8 w2a = packfrag(wr[16 + quad*2], wr[16 + quad*2 + 1]);
            bf16x8 w2b = packfrag(wr[24 + quad*2], wr[24 + quad*2 + 1]);
            f32x4 acc1 = __builtin_amdgcn_mfma_f32_16x16x32_bf16(
                w1a, bb0, (f32x4){0.f,0.f,0.f,0.f}, 0, 0, 0);
            acc1 = __builtin_amdgcn_mfma_f32_16x16x32_bf16(w1b, bb1, acc1, 0, 0, 0);
            f32x4 acc2 = __builtin_amdgcn_mfma_f32_16x16x32_bf16(
                w2a, bb0, (f32x4){0.f,0.f,0.f,0.f}, 0, 0, 0);
            acc2 = __builtin_amdgcn_mfma_f32_16x16x32_bf16(w2b, bb1, acc2, 0, 0, 0);
            // thread holds o = 16*ot + 4*quad + j for n = nw;  y=acc1, z=acc1+acc2
            float z0 = acc1[0]+acc2[0], z1 = acc1[1]+acc2[1],
                  z2 = acc1[2]+acc2[2], z3 = acc1[3]+acc2[3];
            size_t obase = (brow + nw) * 64 + (16*ot + 4*quad);
            *(uint2*)(ybf + obase) = make_uint2(
                bfbits(acc1[0]) | (bfbits(acc1[1]) << 16),
                bfbits(acc1[2]) | (bfbits(acc1[3]) << 16));
            *(uint2*)(zbf + obase) = make_uint2(
                bfbits(z0) | (bfbits(z1) << 16),
                bfbits(z2) | (bfbits(z3) << 16));
        }
    }
}

// ---------------- Kernel 2 (fused): MFMA Gram + top-12 group keys + refine ----------------
// 2048 blocks x 256; b = blockIdx&7 (XCD-affinity swizzle), 16 n-rows per block.
// Transposed MFMA: A = streamed m-tile, B = fixed n-tile -> thread holds 4
// consecutive m for fixed n = n0 + (lane&15): group max is 3 in-thread v_max,
// no LDS round-trip, no barrier in the main loop.
__global__ __launch_bounds__(256, 4) void k_main(
    const unsigned short* __restrict__ xbf, const float* __restrict__ xt,
    const double* __restrict__ xxd, const float* __restrict__ xxc,
    const unsigned short* __restrict__ ybf, const unsigned short* __restrict__ zbf,
    const float* __restrict__ gamma, const float* __restrict__ beta,
    const float* __restrict__ rmean, const float* __restrict__ rvar,
    float* __restrict__ out)
{
    __shared__ __align__(16) unsigned keysL[16 * NCAND];  // 12 KB
    __shared__ __align__(16) unsigned gselS[16 * EXTRG];  // 1.75 KB
    __shared__ int      m26S[16 * NF];                    // 1.66 KB
    __shared__ double   d26S[16 * NF];                    // 3.33 KB
    __shared__ int      selS[16 * KK];                    // 1.25 KB
    __shared__ float    outS[64 * 20];                    // 5 KB

    int tid  = threadIdx.x;
    int w    = tid >> 6, lane = tid & 63;
    int quad = lane >> 4, c = lane & 15;
    int b  = blockIdx.x & 7;                 // batch <-> XCD affinity
    int n0 = (blockIdx.x >> 3) << 4;
    size_t brow = (size_t)b * NN;

    const uint4* xb = (const uint4*)xbf;     // one row = 8 uint4

    // B fragments: fixed n-rows n0+c
    size_t nrow = (brow + n0 + c) * 8 + quad;
    bf16x8 bn0 = __builtin_bit_cast(bf16x8, xb[nrow]);
    bf16x8 bn1 = __builtin_bit_cast(bf16x8, xb[nrow + 4]);

    unsigned keys[LL];
    #pragma unroll
    for (int i = 0; i < LL; ++i) keys[i] = 0u;

    // A stream: m-rows (chunk*64 + 16w + c)
    size_t abase = (brow + 16*w + c) * 8 + quad;
    uint4 pa0 = xb[abase], pa1 = xb[abase + 4];
    float4 pxx4 = *(const float4*)(xxc + brow + 16*w + quad*4);

    #pragma unroll 1
    for (int chunk = 0; chunk < 64; ++chunk) {
        uint4 ca0 = pa0, ca1 = pa1;
        float4 x4 = pxx4;
        if (chunk < 63) {
            size_t nb = abase + (size_t)(chunk + 1) * 512;
            pa0 = xb[nb]; pa1 = xb[nb + 4];
            pxx4 = *(const float4*)(xxc + brow + (chunk+1)*64 + 16*w + quad*4);
        }
        f32x4 acc = __builtin_amdgcn_mfma_f32_16x16x32_bf16(
            __builtin_bit_cast(bf16x8, ca0), bn0, (f32x4){0.f,0.f,0.f,0.f}, 0, 0, 0);
        acc = __builtin_amdgcn_mfma_f32_16x16x32_bf16(
            __builtin_bit_cast(bf16x8, ca1), bn1, acc, 0, 0, 0);

        // thread: n = n0+c, m = chunk*64 + 16w + 4quad + j  (one aligned group of 4)
        float s0 = fmaf(2.f, acc[0], x4.x), s1 = fmaf(2.f, acc[1], x4.y);
        float s2 = fmaf(2.f, acc[2], x4.z), s3 = fmaf(2.f, acc[3], x4.w);
        float gm = fmaxf(fmaxf(s0, s1), fmaxf(s2, s3));
        unsigned key = (__float_as_uint(gm) & 0xFFFFFC00u)
                     | (unsigned)((chunk << 4) | (w << 2) | quad);
        #pragma unroll
        for (int t = 0; t < LL; ++t) {
            unsigned mx = umax_(keys[t], key);
            key = umin_(keys[t], key);
            keys[t] = mx;
        }
    }

    // park lists: row = c, list id = 4w+quad
    {
        uint4* kd = (uint4*)(keysL + c*NCAND + (w*4 + quad)*LL);
        kd[0] = make_uint4(keys[0], keys[1], keys[2],  keys[3]);
        kd[1] = make_uint4(keys[4], keys[5], keys[6],  keys[7]);
        kd[2] = make_uint4(keys[8], keys[9], keys[10], keys[11]);
    }
    __syncthreads();

    // ================= refine (quarter-wave per row) =================
    int r = tid >> 4, g = tid & 15;
    int n = n0 + r;

    unsigned mk[LL];
    {
        const uint4* ks = (const uint4*)(keysL + r*NCAND + g*LL);
        uint4 k0 = ks[0], k1 = ks[1], k2 = ks[2];
        mk[0]=k0.x; mk[1]=k0.y; mk[2]=k0.z;  mk[3]=k0.w;
        mk[4]=k1.x; mk[5]=k1.y; mk[6]=k1.z;  mk[7]=k1.w;
        mk[8]=k2.x; mk[9]=k2.y; mk[10]=k2.z; mk[11]=k2.w;
    }
    uint2 anb = *(const uint2*)(xbf + (brow + n) * 64 + 4*g);
    float an0 = bflo(anb.x), an1 = bfhi(anb.x), an2 = bflo(anb.y), an3 = bfhi(anb.y);
    float4 an4 = *(const float4*)(xt + (brow + n) * 64 + 4*g);

    // stage 2: pop-shift merge of 16 sorted lists -> top-EXTRG groups
    #pragma unroll 1
    for (int it = 0; it < EXTRG; ++it) {
        unsigned vm = rowmax16(mk[0]);
        bool win = (mk[0] == vm);
        #pragma unroll
        for (int q = 0; q < LL-1; ++q) mk[q] = win ? mk[q+1] : mk[q];
        mk[LL-1] = win ? 0u : mk[LL-1];
        if (g == (it & 15)) gselS[r*EXTRG + it] = vm;
    }

    // stage 3: bf16 cooperative rescore of 112 candidates, per-lane 7-lists
    unsigned myk[7];
    #pragma unroll
    for (int j = 0; j < 7; ++j) {
        uint4 Gj = *(const uint4*)(gselS + r*EXTRG + 4*j);
        unsigned gk4[4] = {Gj.x, Gj.y, Gj.z, Gj.w};
        #pragma unroll
        for (int t = 0; t < 16; ++t) {
            unsigned gk = gk4[t >> 2];
            int m = (int)((gk & 1023u) << 2) | (t & 3);
            uint2 vb = *(const uint2*)(xbf + (brow + m) * 64 + 4*g);
            float p = an0 * bflo(vb.x);
            p = fmaf(an1, bfhi(vb.x), p);
            p = fmaf(an2, bflo(vb.y), p);
            p = fmaf(an3, bfhi(vb.y), p);
            p = rowsum16(p);
            float sc = fmaf(2.f, p, xxc[brow + m]);   // biased positive
            unsigned key = (__float_as_uint(sc) & 0xFFFFFF80u) | (unsigned)(j*16 + t);
            if (t == g) myk[j] = key;
        }
    }
    #pragma unroll
    for (int a = 1; a < 7; ++a)
        #pragma unroll
        for (int q = a; q > 0; --q) {
            unsigned lo = umin_(myk[q-1], myk[q]);
            myk[q-1] = umax_(myk[q-1], myk[q]);
            myk[q] = lo;
        }

    // stage 3.5: pop-shift merge -> exact top-NF of the 112 fp32 keys
    #pragma unroll 1
    for (int it = 0; it < NF; ++it) {
        unsigned vm = rowmax16(myk[0]);
        bool win = (myk[0] == vm);
        #pragma unroll
        for (int q = 0; q < 6; ++q) myk[q] = win ? myk[q+1] : myk[q];
        myk[6] = win ? 0u : myk[6];
        if (g == (it & 15)) {
            int i = (int)(vm & 127u);
            unsigned gk = gselS[r*EXTRG + (i >> 2)];
            m26S[r*NF + it] = (int)((gk & 1023u) << 2) | (i & 3);
        }
    }

    // stage 4: fp64 cooperative rescore of NF finalists
    {
        double ax = (double)an4.x, ay = (double)an4.y,
               az = (double)an4.z, aw = (double)an4.w;
        #pragma unroll 2
        for (int t = 0; t < NF; ++t) {
            int m = m26S[r*NF + t];
            float4 v = *(const float4*)(xt + (brow + m) * 64 + 4*g);
            double p = ax*(double)v.x + ay*(double)v.y + az*(double)v.z + aw*(double)v.w;
            p = rowsum16d(p);
            if ((t & 15) == g) d26S[r*NF + t] = 2.0*p - xxd[brow + m];
        }
    }

    // stage 5: exact top-20 set by rank counting
    #pragma unroll 1
    for (int t = g; t < NF; t += 16) {
        double st = d26S[r*NF + t];
        int cnt = 0;
        #pragma unroll
        for (int p = 0; p < NF; ++p) cnt += (d26S[r*NF + p] > st) ? 1 : 0;
        if (cnt < KK) selS[r*KK + cnt] = m26S[r*NF + t];
    }

    // stage 6: gather y (bf16) over 20 neighbors; min & max per o; epilogue
    float mn[4] = { __builtin_inff(), __builtin_inff(), __builtin_inff(), __builtin_inff() };
    float mx[4] = { -__builtin_inff(), -__builtin_inff(), -__builtin_inff(), -__builtin_inff() };
    #pragma unroll 4
    for (int k = 0; k < KK; ++k) {
        int m = selS[r*KK + k];
        uint2 yb = *(const uint2*)(ybf + (brow + m) * 64 + 4*g);
        float y0 = bflo(yb.x), y1 = bfhi(yb.x), y2 = bflo(yb.y), y3 = bfhi(yb.y);
        mn[0] = fminf(mn[0], y0); mx[0] = fmaxf(mx[0], y0);
        mn[1] = fminf(mn[1], y1); mx[1] = fmaxf(mx[1], y1);
        mn[2] = fminf(mn[2], y2); mx[2] = fmaxf(mx[2], y2);
        mn[3] = fminf(mn[3], y3); mx[3] = fmaxf(mx[3], y3);
    }
    uint2 zb = *(const uint2*)(zbf + (brow + n) * 64 + 4*g);
    float zz[4] = {bflo(zb.x), bfhi(zb.x), bflo(zb.y), bfhi(zb.y)};
    #pragma unroll
    for (int j = 0; j < 4; ++j) {
        int o = 4*g + j;
        float inv  = gamma[o] / sqrtf(rvar[o] + 1e-5f);
        float bias = beta[o] - rmean[o] * inv;
        float ysel = (inv >= 0.f) ? mn[j] : mx[j];
        float h = (zz[j] - ysel) * inv + bias;
        outS[o*20 + r] = (h >= 0.f) ? h : 0.2f * h;
    }
    __syncthreads();   // cross-wave: output transpose
    {
        int o = tid >> 2, q = tid & 3;
        float4 v = *(const float4*)(outS + o*20 + 4*q);
        *(float4*)(out + ((size_t)(b*64 + o) << 12) + n0 + 4*q) = v;
    }
}

extern "C" void kernel_launch(void* const* d_in, const int* in_sizes, int n_in,
                              void* d_out, int out_size, void* d_ws, size_t ws_size,
                              hipStream_t stream) {
    const float* x     = (const float*)d_in[0];
    const float* W     = (const float*)d_in[1];
    const float* gamma = (const float*)d_in[2];
    const float* beta  = (const float*)d_in[3];
    const float* rmean = (const float*)d_in[4];
    const float* rvar  = (const float*)d_in[5];
    float* out = (float*)d_out;

    char* ws = (char*)d_ws;
    float*          xt  = (float*)          (ws);                          //  8 MB
    unsigned short* xbf = (unsigned short*) (ws + ((size_t) 8 << 20));     //  4 MB
    unsigned short* ybf = (unsigned short*) (ws + ((size_t)12 << 20));     //  4 MB
    unsigned short* zbf = (unsigned short*) (ws + ((size_t)16 << 20));     //  4 MB
    double*         xxd = (double*)         (ws + ((size_t)20 << 20));     // 256 KB
    float*          xxc = (float*)          (ws + ((size_t)20 << 20) + (512 << 10)); // 128 KB

    k_prep<<< 256, 128, 0, stream>>>(x, W, xt, xbf, ybf, zbf, xxd, xxc);
    k_main<<<2048, 256, 0, stream>>>(xbf, xt, xxd, xxc, ybf, zbf,
                                     gamma, beta, rmean, rvar, out);
}

// Round 7
// 308.742 us; speedup vs baseline: 1.6599x; 1.0210x over previous
//
#include <hip/hip_runtime.h>
#include <hip/hip_bf16.h>

// EdgeConv B=8,C=64,N=4096,OUT=64,K=20.
// h[b,o,n,k] = z[b,n,o] - y[b,idx_k,o];  out = leakyrelu((z - min/max_k y)*inv + bias)
#define NN 4096
#define KK 20
#define LL 12        // per-thread sorted list of GROUP keys (group = 4 consecutive m)
#define NCAND 192    // 16 lists * LL group keys per row
#define EXTRG 24     // groups merged out before rescore (margin 4 over 20 -- exact, see note)
#define NC 96        // EXTRG*4 expanded candidates (bf16 rescore)
#define NF 24        // fp64-rescored finalists (margin 4 over 20)

typedef short bf16x8 __attribute__((ext_vector_type(8)));
typedef float f32x4  __attribute__((ext_vector_type(4)));

__device__ __forceinline__ unsigned umax_(unsigned a, unsigned b){ return a > b ? a : b; }
__device__ __forceinline__ unsigned umin_(unsigned a, unsigned b){ return a < b ? a : b; }

__device__ __forceinline__ unsigned bfbits(float f) {   // fp32 -> bf16 bits, RNE
    unsigned u = __float_as_uint(f);
    return (u + 0x7FFFu + ((u >> 16) & 1u)) >> 16;
}
__device__ __forceinline__ float bflo(unsigned u){ return __builtin_bit_cast(float, u << 16); }
__device__ __forceinline__ float bfhi(unsigned u){ return __builtin_bit_cast(float, u & 0xFFFF0000u); }

__device__ __forceinline__ bf16x8 packfrag(float4 lo, float4 hi) {
    uint4 u = make_uint4(bfbits(lo.x) | (bfbits(lo.y) << 16),
                         bfbits(lo.z) | (bfbits(lo.w) << 16),
                         bfbits(hi.x) | (bfbits(hi.y) << 16),
                         bfbits(hi.z) | (bfbits(hi.w) << 16));
    return __builtin_bit_cast(bf16x8, u);
}

// ---- DPP cross-lane (row = 16 lanes; row_ror:n = 0x120+n) -------------------
template<int CTRL>
__device__ __forceinline__ int dpp_mov(int v) {
    return __builtin_amdgcn_update_dpp(0, v, CTRL, 0xF, 0xF, true);
}
template<int CTRL>
__device__ __forceinline__ float dpp_addf(float v) {
    return v + __builtin_bit_cast(float, dpp_mov<CTRL>(__builtin_bit_cast(int, v)));
}
template<int CTRL>
__device__ __forceinline__ unsigned dpp_maxu(unsigned v) {
    return umax_(v, (unsigned)dpp_mov<CTRL>((int)v));
}
__device__ __forceinline__ float rowsum16(float v) {
    v = dpp_addf<0x128>(v); v = dpp_addf<0x124>(v);
    v = dpp_addf<0x122>(v); v = dpp_addf<0x121>(v);
    return v;
}
__device__ __forceinline__ unsigned rowmax16(unsigned v) {
    v = dpp_maxu<0x128>(v); v = dpp_maxu<0x124>(v);
    v = dpp_maxu<0x122>(v); v = dpp_maxu<0x121>(v);
    return v;
}

// ---------------- Kernel 1a: transpose + xx + bf16 copy ----------------
__global__ __launch_bounds__(128) void k_prep1(
    const float* __restrict__ x,
    float* __restrict__ xt, unsigned short* __restrict__ xbf,
    double* __restrict__ xxd, float* __restrict__ xxc)
{
    int tid = threadIdx.x;
    int fid = blockIdx.x * 128 + tid;          // 0..32767
    int b = fid >> 12, n = fid & 4095;
    size_t brow = (size_t)b * NN;

    float xv[64];
    double xx = 0.0;
    #pragma unroll
    for (int cc = 0; cc < 64; ++cc) {
        float v = x[((size_t)(b*64 + cc) << 12) + n];
        xv[cc] = v;
        xx += (double)v * (double)v;
    }
    size_t rowbase = (brow + n) * 64;
    #pragma unroll
    for (int c4 = 0; c4 < 16; ++c4)
        ((float4*)(xt + rowbase))[c4] =
            make_float4(xv[4*c4], xv[4*c4+1], xv[4*c4+2], xv[4*c4+3]);
    {
        unsigned pk[32];
        #pragma unroll
        for (int i = 0; i < 32; ++i)
            pk[i] = bfbits(xv[2*i]) | (bfbits(xv[2*i+1]) << 16);
        uint4* dst = (uint4*)(xbf + rowbase);
        #pragma unroll
        for (int i = 0; i < 8; ++i)
            dst[i] = make_uint4(pk[4*i], pk[4*i+1], pk[4*i+2], pk[4*i+3]);
    }
    xxd[brow + n] = xx;
    xxc[brow + n] = 1024.f - (float)xx;     // biased so scores are always > 0
}

// ---------------- Kernel 1b: y/z via MFMA from xbf ----------------
// 512 blocks x 256 = 2048 waves; wave handles one 16-n tile.
// A = W rows (o), B = x rows (n): D col=lane&15 -> n, row=quad*4+j -> o.
__global__ __launch_bounds__(256) void k_prep2(
    const float* __restrict__ W, const unsigned short* __restrict__ xbf,
    unsigned short* __restrict__ ybf, unsigned short* __restrict__ zbf)
{
    int tid = threadIdx.x;
    int wv = blockIdx.x * 4 + (tid >> 6);      // 0..2047
    int lane = tid & 63, quad = lane >> 4, c = lane & 15;
    int b = wv >> 8, n0 = (wv & 255) << 4;
    size_t brow = (size_t)b * NN;

    const uint4* xb = (const uint4*)xbf;
    size_t nrow = (brow + n0 + c) * 8 + quad;
    bf16x8 bb0 = __builtin_bit_cast(bf16x8, xb[nrow]);
    bf16x8 bb1 = __builtin_bit_cast(bf16x8, xb[nrow + 4]);

    const float4* W4 = (const float4*)W;       // W row = 32 float4
    #pragma unroll 1
    for (int ot = 0; ot < 4; ++ot) {
        const float4* wr = W4 + (size_t)(ot*16 + c) * 32;
        bf16x8 w1a = packfrag(wr[quad*2],      wr[quad*2 + 1]);
        bf16x8 w1b = packfrag(wr[8 + quad*2],  wr[8 + quad*2 + 1]);
        bf16x8 w2a = packfrag(wr[16 + quad*2], wr[16 + quad*2 + 1]);
        bf16x8 w2b = packfrag(wr[24 + quad*2], wr[24 + quad*2 + 1]);
        f32x4 acc1 = __builtin_amdgcn_mfma_f32_16x16x32_bf16(
            w1a, bb0, (f32x4){0.f,0.f,0.f,0.f}, 0, 0, 0);
        acc1 = __builtin_amdgcn_mfma_f32_16x16x32_bf16(w1b, bb1, acc1, 0, 0, 0);
        f32x4 acc2 = __builtin_amdgcn_mfma_f32_16x16x32_bf16(
            w2a, bb0, (f32x4){0.f,0.f,0.f,0.f}, 0, 0, 0);
        acc2 = __builtin_amdgcn_mfma_f32_16x16x32_bf16(w2b, bb1, acc2, 0, 0, 0);
        // thread (quad,c): o = ot*16 + quad*4 + j, n = n0 + c; y=acc1, z=acc1+acc2
        float z0 = acc1[0]+acc2[0], z1 = acc1[1]+acc2[1],
              z2 = acc1[2]+acc2[2], z3 = acc1[3]+acc2[3];
        size_t obase = (brow + n0 + c) * 64 + (ot*16 + quad*4);
        *(uint2*)(ybf + obase) = make_uint2(
            bfbits(acc1[0]) | (bfbits(acc1[1]) << 16),
            bfbits(acc1[2]) | (bfbits(acc1[3]) << 16));
        *(uint2*)(zbf + obase) = make_uint2(
            bfbits(z0) | (bfbits(z1) << 16),
            bfbits(z2) | (bfbits(z3) << 16));
    }
}

// ---------------- Kernel 2 (fused): MFMA Gram + top-12 group keys + refine ----------------
// 2048 blocks x 256; b = blockIdx&7 (XCD-affinity), 16 n-rows per block.
// A = streamed m-tile (prefetch depth 2), B = fixed n-tile; thread holds 4
// consecutive m for fixed n: in-thread group max, no LDS in the main loop.
// NOTE on EXTRG=24: any group NOT containing a true top-20 element has
// max <= score(rank21) < max of any top-20-bearing group, so the (<=20)
// top-20-bearing groups are exactly the top groups by max; 4-rank margin
// absorbs bf16 noise (group-max spacing ~0.4 >> 2*0.08).
__global__ __launch_bounds__(256, 4) void k_main(
    const unsigned short* __restrict__ xbf, const float* __restrict__ xt,
    const double* __restrict__ xxd, const float* __restrict__ xxc,
    const unsigned short* __restrict__ ybf, const unsigned short* __restrict__ zbf,
    const float* __restrict__ gamma, const float* __restrict__ beta,
    const float* __restrict__ rmean, const float* __restrict__ rvar,
    float* __restrict__ out)
{
    __shared__ __align__(16) unsigned keysL[16 * NCAND];  // 12 KB
    __shared__ __align__(16) unsigned gselS[16 * EXTRG];  // 1.5 KB
    __shared__ int      m26S[16 * NF];                    // 1.5 KB
    __shared__ double   d26S[16 * NF];                    // 3 KB
    __shared__ int      selS[16 * KK];                    // 1.25 KB
    __shared__ float    outS[64 * 20];                    // 5 KB

    int tid  = threadIdx.x;
    int w    = tid >> 6, lane = tid & 63;
    int quad = lane >> 4, c = lane & 15;
    int b  = blockIdx.x & 7;                 // batch <-> XCD affinity
    int n0 = (blockIdx.x >> 3) << 4;
    size_t brow = (size_t)b * NN;

    const uint4* xb = (const uint4*)xbf;     // one row = 8 uint4

    // B fragments: fixed n-rows n0+c
    size_t nrow = (brow + n0 + c) * 8 + quad;
    bf16x8 bn0 = __builtin_bit_cast(bf16x8, xb[nrow]);
    bf16x8 bn1 = __builtin_bit_cast(bf16x8, xb[nrow + 4]);

    unsigned keys[LL];
    #pragma unroll
    for (int i = 0; i < LL; ++i) keys[i] = 0u;

    // A stream with prefetch depth 2
    size_t abase = (brow + 16*w + c) * 8 + quad;
    size_t xxb   = brow + 16*w + quad*4;
    uint4  a0p[2], a1p[2];
    float4 xxp[2];
    a0p[0] = xb[abase];       a1p[0] = xb[abase + 4];
    a0p[1] = xb[abase + 512]; a1p[1] = xb[abase + 516];
    xxp[0] = *(const float4*)(xxc + xxb);
    xxp[1] = *(const float4*)(xxc + xxb + 64);

    #pragma unroll 2
    for (int chunk = 0; chunk < 64; ++chunk) {
        int s = chunk & 1;
        uint4 ca0 = a0p[s], ca1 = a1p[s];
        float4 x4 = xxp[s];
        if (chunk < 62) {
            size_t nb = abase + (size_t)(chunk + 2) * 512;
            a0p[s] = xb[nb]; a1p[s] = xb[nb + 4];
            xxp[s] = *(const float4*)(xxc + xxb + (chunk + 2)*64);
        }
        f32x4 acc = __builtin_amdgcn_mfma_f32_16x16x32_bf16(
            __builtin_bit_cast(bf16x8, ca0), bn0, (f32x4){0.f,0.f,0.f,0.f}, 0, 0, 0);
        acc = __builtin_amdgcn_mfma_f32_16x16x32_bf16(
            __builtin_bit_cast(bf16x8, ca1), bn1, acc, 0, 0, 0);

        // thread: n = n0+c, m = chunk*64 + 16w + 4quad + j  (one aligned group of 4)
        float s0 = fmaf(2.f, acc[0], x4.x), s1 = fmaf(2.f, acc[1], x4.y);
        float s2 = fmaf(2.f, acc[2], x4.z), s3 = fmaf(2.f, acc[3], x4.w);
        float gm = fmaxf(fmaxf(s0, s1), fmaxf(s2, s3));
        unsigned key = (__float_as_uint(gm) & 0xFFFFFC00u)
                     | (unsigned)((chunk << 4) | (w << 2) | quad);
        #pragma unroll
        for (int t = 0; t < LL; ++t) {
            unsigned mx = umax_(keys[t], key);
            key = umin_(keys[t], key);
            keys[t] = mx;
        }
    }

    // park lists: row = c, list id = 4w+quad
    {
        uint4* kd = (uint4*)(keysL + c*NCAND + (w*4 + quad)*LL);
        kd[0] = make_uint4(keys[0], keys[1], keys[2],  keys[3]);
        kd[1] = make_uint4(keys[4], keys[5], keys[6],  keys[7]);
        kd[2] = make_uint4(keys[8], keys[9], keys[10], keys[11]);
    }
    __syncthreads();

    // ================= refine (quarter-wave per row) =================
    int r = tid >> 4, g = tid & 15;
    int n = n0 + r;

    unsigned mk[LL];
    {
        const uint4* ks = (const uint4*)(keysL + r*NCAND + g*LL);
        uint4 k0 = ks[0], k1 = ks[1], k2 = ks[2];
        mk[0]=k0.x; mk[1]=k0.y; mk[2]=k0.z;  mk[3]=k0.w;
        mk[4]=k1.x; mk[5]=k1.y; mk[6]=k1.z;  mk[7]=k1.w;
        mk[8]=k2.x; mk[9]=k2.y; mk[10]=k2.z; mk[11]=k2.w;
    }
    uint2 anb = *(const uint2*)(xbf + (brow + n) * 64 + 4*g);
    float an0 = bflo(anb.x), an1 = bfhi(anb.x), an2 = bflo(anb.y), an3 = bfhi(anb.y);

    // stage 2: pop-shift merge of 16 sorted lists -> top-EXTRG groups
    #pragma unroll 1
    for (int it = 0; it < EXTRG; ++it) {
        unsigned vm = rowmax16(mk[0]);
        bool win = (mk[0] == vm);
        #pragma unroll
        for (int q = 0; q < LL-1; ++q) mk[q] = win ? mk[q+1] : mk[q];
        mk[LL-1] = win ? 0u : mk[LL-1];
        if (g == (it & 15)) gselS[r*EXTRG + it] = vm;
    }

    // stage 3: bf16 cooperative rescore of NC=96 candidates, batched loads
    unsigned myk[6];
    #pragma unroll 1
    for (int j = 0; j < 6; ++j) {
        uint4 Gj = *(const uint4*)(gselS + r*EXTRG + 4*j);
        unsigned gk4[4] = {Gj.x, Gj.y, Gj.z, Gj.w};
        #pragma unroll
        for (int h = 0; h < 2; ++h) {
            uint2 vbs[8]; float xxm[8];
            #pragma unroll
            for (int u = 0; u < 8; ++u) {
                int t = h*8 + u;
                int m = (int)((gk4[t >> 2] & 1023u) << 2) | (t & 3);
                vbs[u] = *(const uint2*)(xbf + (brow + m) * 64 + 4*g);
                xxm[u] = xxc[brow + m];
            }
            #pragma unroll
            for (int u = 0; u < 8; ++u) {
                int t = h*8 + u;
                float p = an0 * bflo(vbs[u].x);
                p = fmaf(an1, bfhi(vbs[u].x), p);
                p = fmaf(an2, bflo(vbs[u].y), p);
                p = fmaf(an3, bfhi(vbs[u].y), p);
                p = rowsum16(p);
                float sc = fmaf(2.f, p, xxm[u]);   // biased positive
                unsigned key = (__float_as_uint(sc) & 0xFFFFFF80u) | (unsigned)(j*16 + t);
                if (t == g) myk[j] = key;
            }
        }
    }
    #pragma unroll
    for (int a = 1; a < 6; ++a)
        #pragma unroll
        for (int q = a; q > 0; --q) {
            unsigned lo = umin_(myk[q-1], myk[q]);
            myk[q-1] = umax_(myk[q-1], myk[q]);
            myk[q] = lo;
        }

    // stage 3.5: pop-shift merge -> exact top-NF of the 96 fp32 keys
    #pragma unroll 1
    for (int it = 0; it < NF; ++it) {
        unsigned vm = rowmax16(myk[0]);
        bool win = (myk[0] == vm);
        #pragma unroll
        for (int q = 0; q < 5; ++q) myk[q] = win ? myk[q+1] : myk[q];
        myk[5] = win ? 0u : myk[5];
        if (g == (it & 15)) {
            int i = (int)(vm & 127u);
            unsigned gk = gselS[r*EXTRG + (i >> 2)];
            m26S[r*NF + it] = (int)((gk & 1023u) << 2) | (i & 3);
        }
    }

    // stage 4: fp64 per-lane full dots (lane = candidate; xn loads are
    // quarter-wave-uniform -> L1 broadcast)
    #pragma unroll 1
    for (int round = 0; round < 2; ++round) {
        int t = round*16 + g;
        if (t < NF) {
            int m = m26S[r*NF + t];
            const float4* xm = (const float4*)(xt + (brow + m) * 64);
            const float4* xn = (const float4*)(xt + (brow + n) * 64);
            double acc = 0.0;
            #pragma unroll
            for (int i = 0; i < 16; ++i) {
                float4 v = xm[i], a = xn[i];
                acc += (double)a.x*(double)v.x + (double)a.y*(double)v.y
                     + (double)a.z*(double)v.z + (double)a.w*(double)v.w;
            }
            d26S[r*NF + t] = 2.0*acc - xxd[brow + m];
        }
    }

    // stage 5: exact top-20 set by rank counting
    #pragma unroll 1
    for (int t = g; t < NF; t += 16) {
        double st = d26S[r*NF + t];
        int cnt = 0;
        #pragma unroll
        for (int p = 0; p < NF; ++p) cnt += (d26S[r*NF + p] > st) ? 1 : 0;
        if (cnt < KK) selS[r*KK + cnt] = m26S[r*NF + t];
    }

    // stage 6: gather y (bf16) over 20 neighbors in 2 batches of 10
    float mn[4] = { __builtin_inff(), __builtin_inff(), __builtin_inff(), __builtin_inff() };
    float mx[4] = { -__builtin_inff(), -__builtin_inff(), -__builtin_inff(), -__builtin_inff() };
    int msel[KK];
    #pragma unroll
    for (int k = 0; k < KK; ++k) msel[k] = selS[r*KK + k];
    #pragma unroll 1
    for (int hb = 0; hb < 2; ++hb) {
        uint2 yb[10];
        #pragma unroll
        for (int k = 0; k < 10; ++k)
            yb[k] = *(const uint2*)(ybf + (brow + msel[hb*10 + k]) * 64 + 4*g);
        #pragma unroll
        for (int k = 0; k < 10; ++k) {
            float y0 = bflo(yb[k].x), y1 = bfhi(yb[k].x),
                  y2 = bflo(yb[k].y), y3 = bfhi(yb[k].y);
            mn[0] = fminf(mn[0], y0); mx[0] = fmaxf(mx[0], y0);
            mn[1] = fminf(mn[1], y1); mx[1] = fmaxf(mx[1], y1);
            mn[2] = fminf(mn[2], y2); mx[2] = fmaxf(mx[2], y2);
            mn[3] = fminf(mn[3], y3); mx[3] = fmaxf(mx[3], y3);
        }
    }
    uint2 zb = *(const uint2*)(zbf + (brow + n) * 64 + 4*g);
    float zz[4] = {bflo(zb.x), bfhi(zb.x), bflo(zb.y), bfhi(zb.y)};
    #pragma unroll
    for (int j = 0; j < 4; ++j) {
        int o = 4*g + j;
        float inv  = gamma[o] / sqrtf(rvar[o] + 1e-5f);
        float bias = beta[o] - rmean[o] * inv;
        float ysel = (inv >= 0.f) ? mn[j] : mx[j];
        float h = (zz[j] - ysel) * inv + bias;
        outS[o*20 + r] = (h >= 0.f) ? h : 0.2f * h;
    }
    __syncthreads();   // cross-wave: output transpose
    {
        int o = tid >> 2, q = tid & 3;
        float4 v = *(const float4*)(outS + o*20 + 4*q);
        *(float4*)(out + ((size_t)(b*64 + o) << 12) + n0 + 4*q) = v;
    }
}

extern "C" void kernel_launch(void* const* d_in, const int* in_sizes, int n_in,
                              void* d_out, int out_size, void* d_ws, size_t ws_size,
                              hipStream_t stream) {
    const float* x     = (const float*)d_in[0];
    const float* W     = (const float*)d_in[1];
    const float* gamma = (const float*)d_in[2];
    const float* beta  = (const float*)d_in[3];
    const float* rmean = (const float*)d_in[4];
    const float* rvar  = (const float*)d_in[5];
    float* out = (float*)d_out;

    char* ws = (char*)d_ws;
    float*          xt  = (float*)          (ws);                          //  8 MB
    unsigned short* xbf = (unsigned short*) (ws + ((size_t) 8 << 20));     //  4 MB
    unsigned short* ybf = (unsigned short*) (ws + ((size_t)12 << 20));     //  4 MB
    unsigned short* zbf = (unsigned short*) (ws + ((size_t)16 << 20));     //  4 MB
    double*         xxd = (double*)         (ws + ((size_t)20 << 20));     // 256 KB
    float*          xxc = (float*)          (ws + ((size_t)20 << 20) + (512 << 10)); // 128 KB

    k_prep1<<< 256, 128, 0, stream>>>(x, xt, xbf, xxd, xxc);
    k_prep2<<< 512, 256, 0, stream>>>(W, xbf, ybf, zbf);
    k_main <<<2048, 256, 0, stream>>>(xbf, xt, xxd, xxc, ybf, zbf,
                                      gamma, beta, rmean, rvar, out);
}

// Round 8
// 303.447 us; speedup vs baseline: 1.6889x; 1.0175x over previous
//
#include <hip/hip_runtime.h>
#include <hip/hip_bf16.h>

// EdgeConv B=8,C=64,N=4096,OUT=64,K=20.
// h[b,o,n,k] = z[b,n,o] - y[b,idx_k,o];  out = leakyrelu((z - min/max_k y)*inv + bias)
#define NN 4096
#define KK 20
#define LL 12        // per-thread sorted list of GROUP keys (group = 4 consecutive m)
#define NCAND 192    // 16 lists * LL group keys per row
#define EXTRG 24     // groups merged out before rescore (margin 4 over 20 -- exact, see note)
#define NF 24        // fp64-rescored finalists (margin 4 over 20)

typedef short bf16x8 __attribute__((ext_vector_type(8)));
typedef float f32x4  __attribute__((ext_vector_type(4)));

__device__ __forceinline__ unsigned umax_(unsigned a, unsigned b){ return a > b ? a : b; }
__device__ __forceinline__ unsigned umin_(unsigned a, unsigned b){ return a < b ? a : b; }

__device__ __forceinline__ unsigned bfbits(float f) {   // fp32 -> bf16 bits, RNE
    unsigned u = __float_as_uint(f);
    return (u + 0x7FFFu + ((u >> 16) & 1u)) >> 16;
}
__device__ __forceinline__ float bflo(unsigned u){ return __builtin_bit_cast(float, u << 16); }
__device__ __forceinline__ float bfhi(unsigned u){ return __builtin_bit_cast(float, u & 0xFFFF0000u); }

__device__ __forceinline__ bf16x8 packfrag(float4 lo, float4 hi) {
    uint4 u = make_uint4(bfbits(lo.x) | (bfbits(lo.y) << 16),
                         bfbits(lo.z) | (bfbits(lo.w) << 16),
                         bfbits(hi.x) | (bfbits(hi.y) << 16),
                         bfbits(hi.z) | (bfbits(hi.w) << 16));
    return __builtin_bit_cast(bf16x8, u);
}

// ---- DPP cross-lane (row = 16 lanes; row_ror:n = 0x120+n) -------------------
template<int CTRL>
__device__ __forceinline__ int dpp_mov(int v) {
    return __builtin_amdgcn_update_dpp(0, v, CTRL, 0xF, 0xF, true);
}
template<int CTRL>
__device__ __forceinline__ float dpp_addf(float v) {
    return v + __builtin_bit_cast(float, dpp_mov<CTRL>(__builtin_bit_cast(int, v)));
}
template<int CTRL>
__device__ __forceinline__ unsigned dpp_maxu(unsigned v) {
    return umax_(v, (unsigned)dpp_mov<CTRL>((int)v));
}
__device__ __forceinline__ float rowsum16(float v) {
    v = dpp_addf<0x128>(v); v = dpp_addf<0x124>(v);
    v = dpp_addf<0x122>(v); v = dpp_addf<0x121>(v);
    return v;
}
__device__ __forceinline__ unsigned rowmax16(unsigned v) {
    v = dpp_maxu<0x128>(v); v = dpp_maxu<0x124>(v);
    v = dpp_maxu<0x122>(v); v = dpp_maxu<0x121>(v);
    return v;
}

// ---------------- Kernel 1a: transpose + xx + bf16 copy ----------------
__global__ __launch_bounds__(128) void k_prep1(
    const float* __restrict__ x,
    float* __restrict__ xt, unsigned short* __restrict__ xbf,
    double* __restrict__ xxd, float* __restrict__ xxc)
{
    int tid = threadIdx.x;
    int fid = blockIdx.x * 128 + tid;          // 0..32767
    int b = fid >> 12, n = fid & 4095;
    size_t brow = (size_t)b * NN;

    float xv[64];
    double xx = 0.0;
    #pragma unroll
    for (int cc = 0; cc < 64; ++cc) {
        float v = x[((size_t)(b*64 + cc) << 12) + n];
        xv[cc] = v;
        xx += (double)v * (double)v;
    }
    size_t rowbase = (brow + n) * 64;
    #pragma unroll
    for (int c4 = 0; c4 < 16; ++c4)
        ((float4*)(xt + rowbase))[c4] =
            make_float4(xv[4*c4], xv[4*c4+1], xv[4*c4+2], xv[4*c4+3]);
    {
        unsigned pk[32];
        #pragma unroll
        for (int i = 0; i < 32; ++i)
            pk[i] = bfbits(xv[2*i]) | (bfbits(xv[2*i+1]) << 16);
        uint4* dst = (uint4*)(xbf + rowbase);
        #pragma unroll
        for (int i = 0; i < 8; ++i)
            dst[i] = make_uint4(pk[4*i], pk[4*i+1], pk[4*i+2], pk[4*i+3]);
    }
    xxd[brow + n] = xx;
    xxc[brow + n] = 1024.f - (float)xx;     // biased so scores are always > 0
}

// ---------------- Kernel 1b: y/z via MFMA from xbf ----------------
__global__ __launch_bounds__(256) void k_prep2(
    const float* __restrict__ W, const unsigned short* __restrict__ xbf,
    unsigned short* __restrict__ ybf, unsigned short* __restrict__ zbf)
{
    int tid = threadIdx.x;
    int wv = blockIdx.x * 4 + (tid >> 6);      // 0..2047
    int lane = tid & 63, quad = lane >> 4, c = lane & 15;
    int b = wv >> 8, n0 = (wv & 255) << 4;
    size_t brow = (size_t)b * NN;

    const uint4* xb = (const uint4*)xbf;
    size_t nrow = (brow + n0 + c) * 8 + quad;
    bf16x8 bb0 = __builtin_bit_cast(bf16x8, xb[nrow]);
    bf16x8 bb1 = __builtin_bit_cast(bf16x8, xb[nrow + 4]);

    const float4* W4 = (const float4*)W;       // W row = 32 float4
    #pragma unroll 1
    for (int ot = 0; ot < 4; ++ot) {
        const float4* wr = W4 + (size_t)(ot*16 + c) * 32;
        bf16x8 w1a = packfrag(wr[quad*2],      wr[quad*2 + 1]);
        bf16x8 w1b = packfrag(wr[8 + quad*2],  wr[8 + quad*2 + 1]);
        bf16x8 w2a = packfrag(wr[16 + quad*2], wr[16 + quad*2 + 1]);
        bf16x8 w2b = packfrag(wr[24 + quad*2], wr[24 + quad*2 + 1]);
        f32x4 acc1 = __builtin_amdgcn_mfma_f32_16x16x32_bf16(
            w1a, bb0, (f32x4){0.f,0.f,0.f,0.f}, 0, 0, 0);
        acc1 = __builtin_amdgcn_mfma_f32_16x16x32_bf16(w1b, bb1, acc1, 0, 0, 0);
        f32x4 acc2 = __builtin_amdgcn_mfma_f32_16x16x32_bf16(
            w2a, bb0, (f32x4){0.f,0.f,0.f,0.f}, 0, 0, 0);
        acc2 = __builtin_amdgcn_mfma_f32_16x16x32_bf16(w2b, bb1, acc2, 0, 0, 0);
        float z0 = acc1[0]+acc2[0], z1 = acc1[1]+acc2[1],
              z2 = acc1[2]+acc2[2], z3 = acc1[3]+acc2[3];
        size_t obase = (brow + n0 + c) * 64 + (ot*16 + quad*4);
        *(uint2*)(ybf + obase) = make_uint2(
            bfbits(acc1[0]) | (bfbits(acc1[1]) << 16),
            bfbits(acc1[2]) | (bfbits(acc1[3]) << 16));
        *(uint2*)(zbf + obase) = make_uint2(
            bfbits(z0) | (bfbits(z1) << 16),
            bfbits(z2) | (bfbits(z3) << 16));
    }
}

// ---------------- Kernel 2 (fused): MFMA Gram + top-12 group keys + refine ----------------
// 2048 blocks x 256; b = blockIdx&7 (XCD-affinity), 16 n-rows per block.
// A = streamed m-tile (prefetch depth 4), B = fixed n-tile.
// ALL register arrays are constant-indexed (fully unrolled loops) -- dynamic
// indexing forces scratch (R7: 41 MB of spill traffic, the round's regression).
__global__ __launch_bounds__(256, 3) void k_main(
    const unsigned short* __restrict__ xbf, const float* __restrict__ xt,
    const double* __restrict__ xxd, const float* __restrict__ xxc,
    const unsigned short* __restrict__ ybf, const unsigned short* __restrict__ zbf,
    const float* __restrict__ gamma, const float* __restrict__ beta,
    const float* __restrict__ rmean, const float* __restrict__ rvar,
    float* __restrict__ out)
{
    __shared__ __align__(16) unsigned keysL[16 * NCAND];  // 12 KB
    __shared__ __align__(16) unsigned gselS[16 * EXTRG];  // 1.5 KB
    __shared__ int      m26S[16 * NF];                    // 1.5 KB
    __shared__ double   d26S[16 * NF];                    // 3 KB
    __shared__ int      selS[16 * KK];                    // 1.25 KB
    __shared__ float    outS[64 * 20];                    // 5 KB

    int tid  = threadIdx.x;
    int w    = tid >> 6, lane = tid & 63;
    int quad = lane >> 4, c = lane & 15;
    int b  = blockIdx.x & 7;                 // batch <-> XCD affinity
    int n0 = (blockIdx.x >> 3) << 4;
    size_t brow = (size_t)b * NN;

    const uint4* xb = (const uint4*)xbf;     // one row = 8 uint4

    // B fragments: fixed n-rows n0+c
    size_t nrow = (brow + n0 + c) * 8 + quad;
    bf16x8 bn0 = __builtin_bit_cast(bf16x8, xb[nrow]);
    bf16x8 bn1 = __builtin_bit_cast(bf16x8, xb[nrow + 4]);

    unsigned keys[LL];
    #pragma unroll
    for (int i = 0; i < LL; ++i) keys[i] = 0u;

    // A stream with prefetch depth 4 (covers ~2 chunk-times > L2 latency)
    size_t abase = (brow + 16*w + c) * 8 + quad;
    size_t xxb   = brow + 16*w + quad*4;
    uint4  a0p[4], a1p[4];
    float4 xxp[4];
    #pragma unroll
    for (int i = 0; i < 4; ++i) {
        a0p[i] = xb[abase + (size_t)i*512];
        a1p[i] = xb[abase + (size_t)i*512 + 4];
        xxp[i] = *(const float4*)(xxc + xxb + i*64);
    }

    #pragma unroll 4
    for (int chunk = 0; chunk < 64; ++chunk) {
        int s = chunk & 3;                   // constant after unroll-4
        uint4 ca0 = a0p[s], ca1 = a1p[s];
        float4 x4 = xxp[s];
        if (chunk < 60) {
            size_t nb = abase + (size_t)(chunk + 4) * 512;
            a0p[s] = xb[nb]; a1p[s] = xb[nb + 4];
            xxp[s] = *(const float4*)(xxc + xxb + (chunk + 4)*64);
        }
        f32x4 acc = __builtin_amdgcn_mfma_f32_16x16x32_bf16(
            __builtin_bit_cast(bf16x8, ca0), bn0, (f32x4){0.f,0.f,0.f,0.f}, 0, 0, 0);
        acc = __builtin_amdgcn_mfma_f32_16x16x32_bf16(
            __builtin_bit_cast(bf16x8, ca1), bn1, acc, 0, 0, 0);

        // thread: n = n0+c, m = chunk*64 + 16w + 4quad + j  (one aligned group of 4)
        float s0 = fmaf(2.f, acc[0], x4.x), s1 = fmaf(2.f, acc[1], x4.y);
        float s2 = fmaf(2.f, acc[2], x4.z), s3 = fmaf(2.f, acc[3], x4.w);
        float gm = fmaxf(fmaxf(s0, s1), fmaxf(s2, s3));
        unsigned key = (__float_as_uint(gm) & 0xFFFFFC00u)
                     | (unsigned)((chunk << 4) | (w << 2) | quad);
        #pragma unroll
        for (int t = 0; t < LL; ++t) {
            unsigned mx = umax_(keys[t], key);
            key = umin_(keys[t], key);
            keys[t] = mx;
        }
    }

    // park lists: row = c, list id = 4w+quad
    {
        uint4* kd = (uint4*)(keysL + c*NCAND + (w*4 + quad)*LL);
        kd[0] = make_uint4(keys[0], keys[1], keys[2],  keys[3]);
        kd[1] = make_uint4(keys[4], keys[5], keys[6],  keys[7]);
        kd[2] = make_uint4(keys[8], keys[9], keys[10], keys[11]);
    }
    __syncthreads();

    // ================= refine (quarter-wave per row) =================
    int r = tid >> 4, g = tid & 15;
    int n = n0 + r;

    unsigned mk[LL];
    {
        const uint4* ks = (const uint4*)(keysL + r*NCAND + g*LL);
        uint4 k0 = ks[0], k1 = ks[1], k2 = ks[2];
        mk[0]=k0.x; mk[1]=k0.y; mk[2]=k0.z;  mk[3]=k0.w;
        mk[4]=k1.x; mk[5]=k1.y; mk[6]=k1.z;  mk[7]=k1.w;
        mk[8]=k2.x; mk[9]=k2.y; mk[10]=k2.z; mk[11]=k2.w;
    }
    uint2 anb = *(const uint2*)(xbf + (brow + n) * 64 + 4*g);
    float an0 = bflo(anb.x), an1 = bfhi(anb.x), an2 = bflo(anb.y), an3 = bfhi(anb.y);

    // stage 2: pop-shift merge of 16 sorted lists -> top-EXTRG groups
    // (mk[] indices do NOT depend on `it` -> stays in registers)
    #pragma unroll 1
    for (int it = 0; it < EXTRG; ++it) {
        unsigned vm = rowmax16(mk[0]);
        bool win = (mk[0] == vm);
        #pragma unroll
        for (int q = 0; q < LL-1; ++q) mk[q] = win ? mk[q+1] : mk[q];
        mk[LL-1] = win ? 0u : mk[LL-1];
        if (g == (it & 15)) gselS[r*EXTRG + it] = vm;
    }

    // stage 3: bf16 cooperative rescore of 96 candidates -- FULLY UNROLLED
    unsigned myk[6];
    #pragma unroll
    for (int j = 0; j < 6; ++j) {
        uint4 Gj = *(const uint4*)(gselS + r*EXTRG + 4*j);
        unsigned gk4[4] = {Gj.x, Gj.y, Gj.z, Gj.w};
        #pragma unroll
        for (int h = 0; h < 2; ++h) {
            uint2 vbs[8]; float xxm[8];
            #pragma unroll
            for (int u = 0; u < 8; ++u) {
                int t = h*8 + u;
                int m = (int)((gk4[t >> 2] & 1023u) << 2) | (t & 3);
                vbs[u] = *(const uint2*)(xbf + (brow + m) * 64 + 4*g);
                xxm[u] = xxc[brow + m];
            }
            #pragma unroll
            for (int u = 0; u < 8; ++u) {
                int t = h*8 + u;
                float p = an0 * bflo(vbs[u].x);
                p = fmaf(an1, bfhi(vbs[u].x), p);
                p = fmaf(an2, bflo(vbs[u].y), p);
                p = fmaf(an3, bfhi(vbs[u].y), p);
                p = rowsum16(p);
                float sc = fmaf(2.f, p, xxm[u]);   // biased positive
                unsigned key = (__float_as_uint(sc) & 0xFFFFFF80u) | (unsigned)(j*16 + t);
                if (t == g) myk[j] = key;
            }
        }
    }
    #pragma unroll
    for (int a = 1; a < 6; ++a)
        #pragma unroll
        for (int q = a; q > 0; --q) {
            unsigned lo = umin_(myk[q-1], myk[q]);
            myk[q-1] = umax_(myk[q-1], myk[q]);
            myk[q] = lo;
        }

    // stage 3.5: pop-shift merge -> exact top-NF of the 96 fp32 keys
    #pragma unroll 1
    for (int it = 0; it < NF; ++it) {
        unsigned vm = rowmax16(myk[0]);
        bool win = (myk[0] == vm);
        #pragma unroll
        for (int q = 0; q < 5; ++q) myk[q] = win ? myk[q+1] : myk[q];
        myk[5] = win ? 0u : myk[5];
        if (g == (it & 15)) {
            int i = (int)(vm & 127u);
            unsigned gk = gselS[r*EXTRG + (i >> 2)];
            m26S[r*NF + it] = (int)((gk & 1023u) << 2) | (i & 3);
        }
    }

    // stage 4: fp64 per-lane full dots (lane = candidate; xn loads are
    // quarter-wave-uniform -> broadcast). Unrolled rounds (t const per round).
    #pragma unroll
    for (int round = 0; round < 2; ++round) {
        int t = round*16 + g;
        if (t < NF) {
            int m = m26S[r*NF + t];
            const float4* xm = (const float4*)(xt + (brow + m) * 64);
            const float4* xn = (const float4*)(xt + (brow + n) * 64);
            double acc = 0.0;
            #pragma unroll
            for (int i = 0; i < 16; ++i) {
                float4 v = xm[i], a = xn[i];
                acc += (double)a.x*(double)v.x + (double)a.y*(double)v.y
                     + (double)a.z*(double)v.z + (double)a.w*(double)v.w;
            }
            d26S[r*NF + t] = 2.0*acc - xxd[brow + m];
        }
    }

    // stage 5: exact top-20 set by rank counting
    #pragma unroll
    for (int round = 0; round < 2; ++round) {
        int t = round*16 + g;
        if (t < NF) {
            double st = d26S[r*NF + t];
            int cnt = 0;
            #pragma unroll
            for (int p = 0; p < NF; ++p) cnt += (d26S[r*NF + p] > st) ? 1 : 0;
            if (cnt < KK) selS[r*KK + cnt] = m26S[r*NF + t];
        }
    }

    // stage 6: gather y (bf16) over 20 neighbors, 2 fully-unrolled batches of 10
    float mn[4] = { __builtin_inff(), __builtin_inff(), __builtin_inff(), __builtin_inff() };
    float mx[4] = { -__builtin_inff(), -__builtin_inff(), -__builtin_inff(), -__builtin_inff() };
    #pragma unroll
    for (int hb = 0; hb < 2; ++hb) {
        uint2 yb[10];
        #pragma unroll
        for (int k = 0; k < 10; ++k)
            yb[k] = *(const uint2*)(ybf + (brow + selS[r*KK + hb*10 + k]) * 64 + 4*g);
        #pragma unroll
        for (int k = 0; k < 10; ++k) {
            float y0 = bflo(yb[k].x), y1 = bfhi(yb[k].x),
                  y2 = bflo(yb[k].y), y3 = bfhi(yb[k].y);
            mn[0] = fminf(mn[0], y0); mx[0] = fmaxf(mx[0], y0);
            mn[1] = fminf(mn[1], y1); mx[1] = fmaxf(mx[1], y1);
            mn[2] = fminf(mn[2], y2); mx[2] = fmaxf(mx[2], y2);
            mn[3] = fminf(mn[3], y3); mx[3] = fmaxf(mx[3], y3);
        }
    }
    uint2 zb = *(const uint2*)(zbf + (brow + n) * 64 + 4*g);
    float zz[4] = {bflo(zb.x), bfhi(zb.x), bflo(zb.y), bfhi(zb.y)};
    #pragma unroll
    for (int j = 0; j < 4; ++j) {
        int o = 4*g + j;
        float inv  = gamma[o] / sqrtf(rvar[o] + 1e-5f);
        float bias = beta[o] - rmean[o] * inv;
        float ysel = (inv >= 0.f) ? mn[j] : mx[j];
        float h = (zz[j] - ysel) * inv + bias;
        outS[o*20 + r] = (h >= 0.f) ? h : 0.2f * h;
    }
    __syncthreads();   // cross-wave: output transpose
    {
        int o = tid >> 2, q = tid & 3;
        float4 v = *(const float4*)(outS + o*20 + 4*q);
        *(float4*)(out + ((size_t)(b*64 + o) << 12) + n0 + 4*q) = v;
    }
}

extern "C" void kernel_launch(void* const* d_in, const int* in_sizes, int n_in,
                              void* d_out, int out_size, void* d_ws, size_t ws_size,
                              hipStream_t stream) {
    const float* x     = (const float*)d_in[0];
    const float* W     = (const float*)d_in[1];
    const float* gamma = (const float*)d_in[2];
    const float* beta  = (const float*)d_in[3];
    const float* rmean = (const float*)d_in[4];
    const float* rvar  = (const float*)d_in[5];
    float* out = (float*)d_out;

    char* ws = (char*)d_ws;
    float*          xt  = (float*)          (ws);                          //  8 MB
    unsigned short* xbf = (unsigned short*) (ws + ((size_t) 8 << 20));     //  4 MB
    unsigned short* ybf = (unsigned short*) (ws + ((size_t)12 << 20));     //  4 MB
    unsigned short* zbf = (unsigned short*) (ws + ((size_t)16 << 20));     //  4 MB
    double*         xxd = (double*)         (ws + ((size_t)20 << 20));     // 256 KB
    float*          xxc = (float*)          (ws + ((size_t)20 << 20) + (512 << 10)); // 128 KB

    k_prep1<<< 256, 128, 0, stream>>>(x, xt, xbf, xxd, xxc);
    k_prep2<<< 512, 256, 0, stream>>>(W, xbf, ybf, zbf);
    k_main <<<2048, 256, 0, stream>>>(xbf, xt, xxd, xxc, ybf, zbf,
                                      gamma, beta, rmean, rvar, out);
}

// Round 9
// 240.300 us; speedup vs baseline: 2.1327x; 1.2628x over previous
//
#include <hip/hip_runtime.h>
#include <hip/hip_bf16.h>

// EdgeConv B=8,C=64,N=4096,OUT=64,K=20.
// h[b,o,n,k] = z[b,n,o] - y[b,idx_k,o];  out = leakyrelu((z - min/max_k y)*inv + bias)
#define NN 4096
#define KK 20
#define LL 12        // per-thread sorted list of GROUP keys (group = 4 consecutive m)
#define KP 196       // keysL row pitch in dwords (192 keys + 4 pad: breaks 16-way bank alias)
#define EXTRG 24     // groups merged out before rescore (exact: bearing groups are top-<=20)
#define NF 24        // fp64-rescored finalists

typedef short bf16x8 __attribute__((ext_vector_type(8)));
typedef float f32x4  __attribute__((ext_vector_type(4)));

__device__ __forceinline__ unsigned umax_(unsigned a, unsigned b){ return a > b ? a : b; }
__device__ __forceinline__ unsigned umin_(unsigned a, unsigned b){ return a < b ? a : b; }

__device__ __forceinline__ unsigned bfbits(float f) {   // fp32 -> bf16 bits, RNE
    unsigned u = __float_as_uint(f);
    return (u + 0x7FFFu + ((u >> 16) & 1u)) >> 16;
}
__device__ __forceinline__ float bflo(unsigned u){ return __builtin_bit_cast(float, u << 16); }
__device__ __forceinline__ float bfhi(unsigned u){ return __builtin_bit_cast(float, u & 0xFFFF0000u); }

__device__ __forceinline__ bf16x8 packfrag(float4 lo, float4 hi) {
    uint4 u = make_uint4(bfbits(lo.x) | (bfbits(lo.y) << 16),
                         bfbits(lo.z) | (bfbits(lo.w) << 16),
                         bfbits(hi.x) | (bfbits(hi.y) << 16),
                         bfbits(hi.z) | (bfbits(hi.w) << 16));
    return __builtin_bit_cast(bf16x8, u);
}

// ---- DPP cross-lane (row = 16 lanes; row_ror:n = 0x120+n) -------------------
template<int CTRL>
__device__ __forceinline__ int dpp_mov(int v) {
    return __builtin_amdgcn_update_dpp(0, v, CTRL, 0xF, 0xF, true);
}
template<int CTRL>
__device__ __forceinline__ float dpp_addf(float v) {
    return v + __builtin_bit_cast(float, dpp_mov<CTRL>(__builtin_bit_cast(int, v)));
}
template<int CTRL>
__device__ __forceinline__ unsigned dpp_maxu(unsigned v) {
    return umax_(v, (unsigned)dpp_mov<CTRL>((int)v));
}
__device__ __forceinline__ float rowsum16(float v) {
    v = dpp_addf<0x128>(v); v = dpp_addf<0x124>(v);
    v = dpp_addf<0x122>(v); v = dpp_addf<0x121>(v);
    return v;
}
__device__ __forceinline__ unsigned rowmax16(unsigned v) {
    v = dpp_maxu<0x128>(v); v = dpp_maxu<0x124>(v);
    v = dpp_maxu<0x122>(v); v = dpp_maxu<0x121>(v);
    return v;
}

// ---------------- Kernel 1a: transpose + xx + bf16, line-coalesced stores ----------------
// 256 blocks x 128 threads. Thread owns one n-row; stores re-shaped through LDS so
// every global store instruction covers contiguous 128B-line segments (R8's direct
// transposed stores touched 128 lines per instr at 16B each -> ~5x write inflation).
__global__ __launch_bounds__(128) void k_prep1(
    const float* __restrict__ x,
    float* __restrict__ xt, unsigned short* __restrict__ xbf,
    double* __restrict__ xxd, float* __restrict__ xxc)
{
    __shared__ __align__(16) float tS[128 * 33];
    int tid = threadIdx.x;
    int b   = blockIdx.x >> 5;
    int nb0 = (blockIdx.x & 31) << 7;
    int n   = nb0 + tid;
    size_t brow = (size_t)b * NN;

    float xv[64];
    double xx = 0.0;
    #pragma unroll
    for (int cc = 0; cc < 64; ++cc) {
        float v = x[((size_t)(b*64 + cc) << 12) + n];
        xv[cc] = v;
        xx += (double)v * (double)v;
    }
    xxd[brow + n] = xx;
    xxc[brow + n] = 1024.f - (float)xx;     // biased so scores are always > 0

    // fp32 xt: two 32-channel halves through LDS
    #pragma unroll 1
    for (int h = 0; h < 2; ++h) {
        #pragma unroll
        for (int cc = 0; cc < 32; ++cc) tS[tid*33 + cc] = xv[h*32 + cc];
        __syncthreads();
        #pragma unroll
        for (int i = 0; i < 8; ++i) {
            int idx = i*128 + tid;              // 0..1023 float4s
            int r = idx >> 3, c4 = idx & 7;
            float4 v = make_float4(tS[r*33 + 4*c4],     tS[r*33 + 4*c4 + 1],
                                   tS[r*33 + 4*c4 + 2], tS[r*33 + 4*c4 + 3]);
            *(float4*)(xt + (brow + nb0 + r)*64 + h*32 + 4*c4) = v;
        }
        __syncthreads();
    }
    // bf16 xbf through LDS
    {
        unsigned pk[32];
        #pragma unroll
        for (int i = 0; i < 32; ++i)
            pk[i] = bfbits(xv[2*i]) | (bfbits(xv[2*i+1]) << 16);
        unsigned* tU = (unsigned*)tS;
        #pragma unroll
        for (int i = 0; i < 32; ++i) tU[tid*33 + i] = pk[i];
        __syncthreads();
        uint4* xb4 = (uint4*)xbf;
        #pragma unroll
        for (int i = 0; i < 8; ++i) {
            int idx = i*128 + tid;
            int r = idx >> 3, u4 = idx & 7;
            uint4 v = make_uint4(tU[r*33 + 4*u4],     tU[r*33 + 4*u4 + 1],
                                 tU[r*33 + 4*u4 + 2], tU[r*33 + 4*u4 + 3]);
            xb4[(brow + nb0 + r)*8 + u4] = v;
        }
    }
}

// ---------------- Kernel 1b: y/z via MFMA from xbf (unchanged) ----------------
__global__ __launch_bounds__(256) void k_prep2(
    const float* __restrict__ W, const unsigned short* __restrict__ xbf,
    unsigned short* __restrict__ ybf, unsigned short* __restrict__ zbf)
{
    int tid = threadIdx.x;
    int wv = blockIdx.x * 4 + (tid >> 6);      // 0..2047
    int lane = tid & 63, quad = lane >> 4, c = lane & 15;
    int b = wv >> 8, n0 = (wv & 255) << 4;
    size_t brow = (size_t)b * NN;

    const uint4* xb = (const uint4*)xbf;
    size_t nrow = (brow + n0 + c) * 8 + quad;
    bf16x8 bb0 = __builtin_bit_cast(bf16x8, xb[nrow]);
    bf16x8 bb1 = __builtin_bit_cast(bf16x8, xb[nrow + 4]);

    const float4* W4 = (const float4*)W;       // W row = 32 float4
    #pragma unroll 1
    for (int ot = 0; ot < 4; ++ot) {
        const float4* wr = W4 + (size_t)(ot*16 + c) * 32;
        bf16x8 w1a = packfrag(wr[quad*2],      wr[quad*2 + 1]);
        bf16x8 w1b = packfrag(wr[8 + quad*2],  wr[8 + quad*2 + 1]);
        bf16x8 w2a = packfrag(wr[16 + quad*2], wr[16 + quad*2 + 1]);
        bf16x8 w2b = packfrag(wr[24 + quad*2], wr[24 + quad*2 + 1]);
        f32x4 acc1 = __builtin_amdgcn_mfma_f32_16x16x32_bf16(
            w1a, bb0, (f32x4){0.f,0.f,0.f,0.f}, 0, 0, 0);
        acc1 = __builtin_amdgcn_mfma_f32_16x16x32_bf16(w1b, bb1, acc1, 0, 0, 0);
        f32x4 acc2 = __builtin_amdgcn_mfma_f32_16x16x32_bf16(
            w2a, bb0, (f32x4){0.f,0.f,0.f,0.f}, 0, 0, 0);
        acc2 = __builtin_amdgcn_mfma_f32_16x16x32_bf16(w2b, bb1, acc2, 0, 0, 0);
        float z0 = acc1[0]+acc2[0], z1 = acc1[1]+acc2[1],
              z2 = acc1[2]+acc2[2], z3 = acc1[3]+acc2[3];
        size_t obase = (brow + n0 + c) * 64 + (ot*16 + quad*4);
        *(uint2*)(ybf + obase) = make_uint2(
            bfbits(acc1[0]) | (bfbits(acc1[1]) << 16),
            bfbits(acc1[2]) | (bfbits(acc1[3]) << 16));
        *(uint2*)(zbf + obase) = make_uint2(
            bfbits(z0) | (bfbits(z1) << 16),
            bfbits(z2) | (bfbits(z3) << 16));
    }
}

// ---------------- Kernel 2 (fused): 32-n tile Gram + top-12 keys + refine ----------------
// 1024 blocks x 256 = exactly 4 blocks/CU for one full residency round (no tail).
// Each block: 32 n-rows (two 16-n B-tiles), full 4096-m stream -> A-traffic halved vs R8.
// outS aliases keysL (dead after refine pass 1) to stay under 40KB LDS.
__global__ __launch_bounds__(256, 4) void k_main(
    const unsigned short* __restrict__ xbf, const float* __restrict__ xt,
    const double* __restrict__ xxd, const float* __restrict__ xxc,
    const unsigned short* __restrict__ ybf, const unsigned short* __restrict__ zbf,
    const float* __restrict__ gamma, const float* __restrict__ beta,
    const float* __restrict__ rmean, const float* __restrict__ rvar,
    float* __restrict__ out)
{
    __shared__ __align__(16) unsigned keysL[32 * KP];     // 25088 B (outS aliases this)
    __shared__ __align__(16) unsigned gselS[32 * EXTRG];  // 3 KB
    __shared__ int      m26S[32 * NF];                    // 3 KB
    __shared__ double   d26S[32 * NF];                    // 6 KB
    __shared__ int      selS[32 * KK];                    // 2.5 KB
    float* outS = (float*)keysL;                          // 64 o x pitch 33 = 8448 B

    int tid  = threadIdx.x;
    int w    = tid >> 6, lane = tid & 63;
    int quad = lane >> 4, c = lane & 15;
    int b  = blockIdx.x & 7;                 // batch <-> XCD affinity
    int n0 = (blockIdx.x >> 3) << 5;         // 32-n tile
    size_t brow = (size_t)b * NN;

    const uint4* xb = (const uint4*)xbf;     // one row = 8 uint4

    // B fragments for the two fixed n-tiles
    size_t nr0 = (brow + n0 + c) * 8 + quad;
    size_t nr1 = (brow + n0 + 16 + c) * 8 + quad;
    bf16x8 b00 = __builtin_bit_cast(bf16x8, xb[nr0]);
    bf16x8 b01 = __builtin_bit_cast(bf16x8, xb[nr0 + 4]);
    bf16x8 b10 = __builtin_bit_cast(bf16x8, xb[nr1]);
    bf16x8 b11 = __builtin_bit_cast(bf16x8, xb[nr1 + 4]);

    unsigned kA[LL], kB[LL];
    #pragma unroll
    for (int i = 0; i < LL; ++i) { kA[i] = 0u; kB[i] = 0u; }

    // A stream, prefetch depth 2
    size_t abase = (brow + 16*w + c) * 8 + quad;
    size_t xxb   = brow + 16*w + quad*4;
    uint4  a0p[2], a1p[2];
    float4 xxp[2];
    a0p[0] = xb[abase];       a1p[0] = xb[abase + 4];
    a0p[1] = xb[abase + 512]; a1p[1] = xb[abase + 516];
    xxp[0] = *(const float4*)(xxc + xxb);
    xxp[1] = *(const float4*)(xxc + xxb + 64);

    #pragma unroll 2
    for (int chunk = 0; chunk < 64; ++chunk) {
        int s = chunk & 1;                   // constant after unroll-2
        uint4 ca0 = a0p[s], ca1 = a1p[s];
        float4 x4 = xxp[s];
        if (chunk < 62) {
            size_t nb = abase + (size_t)(chunk + 2) * 512;
            a0p[s] = xb[nb]; a1p[s] = xb[nb + 4];
            xxp[s] = *(const float4*)(xxc + xxb + (chunk + 2)*64);
        }
        f32x4 accA = __builtin_amdgcn_mfma_f32_16x16x32_bf16(
            __builtin_bit_cast(bf16x8, ca0), b00, (f32x4){0.f,0.f,0.f,0.f}, 0, 0, 0);
        accA = __builtin_amdgcn_mfma_f32_16x16x32_bf16(
            __builtin_bit_cast(bf16x8, ca1), b01, accA, 0, 0, 0);
        f32x4 accB = __builtin_amdgcn_mfma_f32_16x16x32_bf16(
            __builtin_bit_cast(bf16x8, ca0), b10, (f32x4){0.f,0.f,0.f,0.f}, 0, 0, 0);
        accB = __builtin_amdgcn_mfma_f32_16x16x32_bf16(
            __builtin_bit_cast(bf16x8, ca1), b11, accB, 0, 0, 0);

        unsigned gid = (unsigned)((chunk << 4) | (w << 2) | quad);
        {   // tile 0: n = n0+c
            float s0 = fmaf(2.f, accA[0], x4.x), s1 = fmaf(2.f, accA[1], x4.y);
            float s2 = fmaf(2.f, accA[2], x4.z), s3 = fmaf(2.f, accA[3], x4.w);
            float gm = fmaxf(fmaxf(s0, s1), fmaxf(s2, s3));
            unsigned key = (__float_as_uint(gm) & 0xFFFFFC00u) | gid;
            #pragma unroll
            for (int t = 0; t < LL; ++t) {
                unsigned mx = umax_(kA[t], key);
                key = umin_(kA[t], key);
                kA[t] = mx;
            }
        }
        {   // tile 1: n = n0+16+c  (independent CE chain - interleaves with tile 0)
            float s0 = fmaf(2.f, accB[0], x4.x), s1 = fmaf(2.f, accB[1], x4.y);
            float s2 = fmaf(2.f, accB[2], x4.z), s3 = fmaf(2.f, accB[3], x4.w);
            float gm = fmaxf(fmaxf(s0, s1), fmaxf(s2, s3));
            unsigned key = (__float_as_uint(gm) & 0xFFFFFC00u) | gid;
            #pragma unroll
            for (int t = 0; t < LL; ++t) {
                unsigned mx = umax_(kB[t], key);
                key = umin_(kB[t], key);
                kB[t] = mx;
            }
        }
    }

    // park lists: row = 16*tile + c, list id = 4w+quad
    {
        uint4* kd0 = (uint4*)(keysL + c*KP + (w*4 + quad)*LL);
        kd0[0] = make_uint4(kA[0], kA[1], kA[2],  kA[3]);
        kd0[1] = make_uint4(kA[4], kA[5], kA[6],  kA[7]);
        kd0[2] = make_uint4(kA[8], kA[9], kA[10], kA[11]);
        uint4* kd1 = (uint4*)(keysL + (16 + c)*KP + (w*4 + quad)*LL);
        kd1[0] = make_uint4(kB[0], kB[1], kB[2],  kB[3]);
        kd1[1] = make_uint4(kB[4], kB[5], kB[6],  kB[7]);
        kd1[2] = make_uint4(kB[8], kB[9], kB[10], kB[11]);
    }
    __syncthreads();

    // ================= refine (quarter-wave per row; 2 rows per thread-group) ========
    int r = tid >> 4, g = tid & 15;

    // pass 1: stage 1+2 for both rows -> gselS; after this keysL is dead
    #pragma unroll 1
    for (int rr = 0; rr < 2; ++rr) {
        int row = rr*16 + r;
        unsigned mk[LL];
        {
            const uint4* ks = (const uint4*)(keysL + row*KP + g*LL);
            uint4 k0 = ks[0], k1 = ks[1], k2 = ks[2];
            mk[0]=k0.x; mk[1]=k0.y; mk[2]=k0.z;  mk[3]=k0.w;
            mk[4]=k1.x; mk[5]=k1.y; mk[6]=k1.z;  mk[7]=k1.w;
            mk[8]=k2.x; mk[9]=k2.y; mk[10]=k2.z; mk[11]=k2.w;
        }
        #pragma unroll 1
        for (int it = 0; it < EXTRG; ++it) {
            unsigned vm = rowmax16(mk[0]);
            bool win = (mk[0] == vm);
            #pragma unroll
            for (int q = 0; q < LL-1; ++q) mk[q] = win ? mk[q+1] : mk[q];
            mk[LL-1] = win ? 0u : mk[LL-1];
            if (g == (it & 15)) gselS[row*EXTRG + it] = vm;
        }
    }
    __syncthreads();   // keysL reads done -> outS (alias) may now be written

    // pass 2: stages 3..6 per row
    #pragma unroll 1
    for (int rr = 0; rr < 2; ++rr) {
        int row = rr*16 + r;
        int n = n0 + row;
        uint2 anb = *(const uint2*)(xbf + (brow + n) * 64 + 4*g);
        float an0 = bflo(anb.x), an1 = bfhi(anb.x),
              an2 = bflo(anb.y), an3 = bfhi(anb.y);

        // stage 3: bf16 cooperative rescore of 96 candidates
        unsigned myk[6];
        #pragma unroll
        for (int j = 0; j < 6; ++j) {
            uint4 Gj = *(const uint4*)(gselS + row*EXTRG + 4*j);
            unsigned gk4[4] = {Gj.x, Gj.y, Gj.z, Gj.w};
            #pragma unroll
            for (int h = 0; h < 2; ++h) {
                uint2 vbs[8]; float xxm[8];
                #pragma unroll
                for (int u = 0; u < 8; ++u) {
                    int t = h*8 + u;
                    int m = (int)((gk4[t >> 2] & 1023u) << 2) | (t & 3);
                    vbs[u] = *(const uint2*)(xbf + (brow + m) * 64 + 4*g);
                    xxm[u] = xxc[brow + m];
                }
                #pragma unroll
                for (int u = 0; u < 8; ++u) {
                    int t = h*8 + u;
                    float p = an0 * bflo(vbs[u].x);
                    p = fmaf(an1, bfhi(vbs[u].x), p);
                    p = fmaf(an2, bflo(vbs[u].y), p);
                    p = fmaf(an3, bfhi(vbs[u].y), p);
                    p = rowsum16(p);
                    float sc = fmaf(2.f, p, xxm[u]);
                    unsigned key = (__float_as_uint(sc) & 0xFFFFFF80u) | (unsigned)(j*16 + t);
                    if (t == g) myk[j] = key;
                }
            }
        }
        #pragma unroll
        for (int a = 1; a < 6; ++a)
            #pragma unroll
            for (int q = a; q > 0; --q) {
                unsigned lo = umin_(myk[q-1], myk[q]);
                myk[q-1] = umax_(myk[q-1], myk[q]);
                myk[q] = lo;
            }

        // stage 3.5: pop-shift merge -> exact top-NF of the 96 fp32 keys
        #pragma unroll 1
        for (int it = 0; it < NF; ++it) {
            unsigned vm = rowmax16(myk[0]);
            bool win = (myk[0] == vm);
            #pragma unroll
            for (int q = 0; q < 5; ++q) myk[q] = win ? myk[q+1] : myk[q];
            myk[5] = win ? 0u : myk[5];
            if (g == (it & 15)) {
                int i = (int)(vm & 127u);
                unsigned gk = gselS[row*EXTRG + (i >> 2)];
                m26S[row*NF + it] = (int)((gk & 1023u) << 2) | (i & 3);
            }
        }

        // stage 4: fp64 per-lane full dots (lane = candidate)
        #pragma unroll
        for (int round = 0; round < 2; ++round) {
            int t = round*16 + g;
            if (t < NF) {
                int m = m26S[row*NF + t];
                const float4* xm = (const float4*)(xt + (brow + m) * 64);
                const float4* xn = (const float4*)(xt + (brow + n) * 64);
                double acc = 0.0;
                #pragma unroll
                for (int i = 0; i < 16; ++i) {
                    float4 v = xm[i], a = xn[i];
                    acc += (double)a.x*(double)v.x + (double)a.y*(double)v.y
                         + (double)a.z*(double)v.z + (double)a.w*(double)v.w;
                }
                d26S[row*NF + t] = 2.0*acc - xxd[brow + m];
            }
        }

        // stage 5: exact top-20 set by rank counting
        #pragma unroll
        for (int round = 0; round < 2; ++round) {
            int t = round*16 + g;
            if (t < NF) {
                double st = d26S[row*NF + t];
                int cnt = 0;
                #pragma unroll
                for (int p = 0; p < NF; ++p) cnt += (d26S[row*NF + p] > st) ? 1 : 0;
                if (cnt < KK) selS[row*KK + cnt] = m26S[row*NF + t];
            }
        }

        // stage 6: gather y (bf16), min/max per o, epilogue -> outS (aliased)
        float mn[4] = { __builtin_inff(), __builtin_inff(), __builtin_inff(), __builtin_inff() };
        float mx[4] = { -__builtin_inff(), -__builtin_inff(), -__builtin_inff(), -__builtin_inff() };
        #pragma unroll
        for (int hb = 0; hb < 2; ++hb) {
            uint2 yb[10];
            #pragma unroll
            for (int k = 0; k < 10; ++k)
                yb[k] = *(const uint2*)(ybf + (brow + selS[row*KK + hb*10 + k]) * 64 + 4*g);
            #pragma unroll
            for (int k = 0; k < 10; ++k) {
                float y0 = bflo(yb[k].x), y1 = bfhi(yb[k].x),
                      y2 = bflo(yb[k].y), y3 = bfhi(yb[k].y);
                mn[0] = fminf(mn[0], y0); mx[0] = fmaxf(mx[0], y0);
                mn[1] = fminf(mn[1], y1); mx[1] = fmaxf(mx[1], y1);
                mn[2] = fminf(mn[2], y2); mx[2] = fmaxf(mx[2], y2);
                mn[3] = fminf(mn[3], y3); mx[3] = fmaxf(mx[3], y3);
            }
        }
        uint2 zb = *(const uint2*)(zbf + (brow + n) * 64 + 4*g);
        float zz[4] = {bflo(zb.x), bfhi(zb.x), bflo(zb.y), bfhi(zb.y)};
        #pragma unroll
        for (int j = 0; j < 4; ++j) {
            int o = 4*g + j;
            float inv  = gamma[o] / sqrtf(rvar[o] + 1e-5f);
            float bias = beta[o] - rmean[o] * inv;
            float ysel = (inv >= 0.f) ? mn[j] : mx[j];
            float h = (zz[j] - ysel) * inv + bias;
            outS[o*33 + row] = (h >= 0.f) ? h : 0.2f * h;
        }
    }
    __syncthreads();   // cross-wave: output transpose
    {
        int o = tid >> 2, q = tid & 3;
        float* ob = outS + o*33;
        float4 v0 = make_float4(ob[4*q],      ob[4*q + 1],  ob[4*q + 2],  ob[4*q + 3]);
        float4 v1 = make_float4(ob[16 + 4*q], ob[17 + 4*q], ob[18 + 4*q], ob[19 + 4*q]);
        float* op = out + ((size_t)(b*64 + o) << 12) + n0;
        *(float4*)(op + 4*q)      = v0;
        *(float4*)(op + 16 + 4*q) = v1;
    }
}

extern "C" void kernel_launch(void* const* d_in, const int* in_sizes, int n_in,
                              void* d_out, int out_size, void* d_ws, size_t ws_size,
                              hipStream_t stream) {
    const float* x     = (const float*)d_in[0];
    const float* W     = (const float*)d_in[1];
    const float* gamma = (const float*)d_in[2];
    const float* beta  = (const float*)d_in[3];
    const float* rmean = (const float*)d_in[4];
    const float* rvar  = (const float*)d_in[5];
    float* out = (float*)d_out;

    char* ws = (char*)d_ws;
    float*          xt  = (float*)          (ws);                          //  8 MB
    unsigned short* xbf = (unsigned short*) (ws + ((size_t) 8 << 20));     //  4 MB
    unsigned short* ybf = (unsigned short*) (ws + ((size_t)12 << 20));     //  4 MB
    unsigned short* zbf = (unsigned short*) (ws + ((size_t)16 << 20));     //  4 MB
    double*         xxd = (double*)         (ws + ((size_t)20 << 20));     // 256 KB
    float*          xxc = (float*)          (ws + ((size_t)20 << 20) + (512 << 10)); // 128 KB

    k_prep1<<< 256, 128, 0, stream>>>(x, xt, xbf, xxd, xxc);
    k_prep2<<< 512, 256, 0, stream>>>(W, xbf, ybf, zbf);
    k_main <<<1024, 256, 0, stream>>>(xbf, xt, xxd, xxc, ybf, zbf,
                                      gamma, beta, rmean, rvar, out);
}